// Round 7
// baseline (12069.352 us; speedup 1.0000x reference)
//
#include <hip/hip_runtime.h>
#include <cmath>

#define B_ 256
#define T_ 256
#define F_ 40
#define H_ 256
#define A_ 64
#define HOR_ 60
#define DSP_ 192
#define ENC_NBLK 128
#define GRP_SZ 16     // blocks per enc barrier group (one dir x mtile)
#define WSTR 456      // LDS weight row stride in u16 (448 + pad)

typedef unsigned short u16;
typedef unsigned int u32;
typedef __attribute__((ext_vector_type(8))) short bf16x8;
typedef __attribute__((ext_vector_type(4))) float f32x4;
typedef __attribute__((ext_vector_type(8))) u32 u32x8;
typedef __attribute__((ext_vector_type(4))) u32 u32x4;

__device__ __forceinline__ float sigm(float x){ return 1.f/(1.f+expf(-x)); }

__device__ __forceinline__ u16 f2bf(float x){
  u32 u = __float_as_uint(x);
  u32 r = (u + 0x7FFFu + ((u>>16)&1u)) >> 16;
  return (u16)r;
}
__device__ __forceinline__ float bf2f(u16 h){ return __uint_as_float(((u32)h)<<16); }
__device__ __forceinline__ u32 packsplit(float x){
  u16 hi = f2bf(x);
  u16 lo = f2bf(x - bf2f(hi));
  return (u32)hi | ((u32)lo<<16);
}
__device__ __forceinline__ float unpack2f(u32 v){
  return __uint_as_float(v<<16) + __uint_as_float(v & 0xFFFF0000u);
}

__device__ __forceinline__ float wred_sum(float v){
  #pragma unroll
  for (int o=32;o>0;o>>=1) v += __shfl_xor(v,o);
  return v;
}
__device__ __forceinline__ float wred_max(float v){
  #pragma unroll
  for (int o=32;o>0;o>>=1) v = fmaxf(v,__shfl_xor(v,o));
  return v;
}

// ---- weight conversion: dst[n][k] (hi/lo bf16) = src[k][n], src = [Wx ; Wh] ----
__global__ void conv_w(const float* __restrict__ Wx, const float* __restrict__ Wh,
                       u16* __restrict__ hi, u16* __restrict__ lo,
                       int KX, int Ktot, int N){
  int idx = blockIdx.x*256 + threadIdx.x;
  if (idx >= N*Ktot) return;
  int n = idx / Ktot, k = idx - n*Ktot;
  float w = (k < KX) ? Wx[(size_t)k*N + n] : Wh[(size_t)(k-KX)*N + n];
  u16 h = f2bf(w);
  hi[idx] = h;
  lo[idx] = f2bf(w - bf2f(h));
}

// ---- spatial projection: hsp32[t][b][192] packed = x[b][t][:40] @ W_sp + b_sp ----
__global__ __launch_bounds__(192) void spatial_proj(
    const float* __restrict__ x, const float* __restrict__ W, const float* __restrict__ bsp,
    u32* __restrict__ hsp32){
  __shared__ float Ws[40][192];
  __shared__ float xr[40];
  int t = blockIdx.x, tid = threadIdx.x;
  for (int i = tid; i < 40*192; i += 192){ int k = i/192, c = i-k*192; Ws[k][c] = W[i]; }
  float bb = bsp[tid];
  __syncthreads();
  for (int b=0; b<B_; b++){
    if (tid < 40) xr[tid] = x[((size_t)b*T_ + t)*F_ + tid];
    __syncthreads();
    float acc = bb;
    #pragma unroll
    for (int k=0;k<40;k++) acc += xr[k]*Ws[k][tid];
    hsp32[((size_t)t*B_ + b)*DSP_ + tid] = packsplit(acc);
    __syncthreads();
  }
}

// ---- persistent bidirectional encoder scan (round-4 proven version, unchanged) ----
__global__ __launch_bounds__(256) void enc_scan(
    const u32* __restrict__ hsp32,
    const u16* __restrict__ W_hi, const u16* __restrict__ W_lo,
    const float* __restrict__ b_ef, const float* __restrict__ b_eb,
    u32* __restrict__ hbuf, u32* __restrict__ eo32, int* __restrict__ bar)
{
  extern __shared__ u16 smem[];
  u16* Whi = smem;                    // [4 gates][16 units][WSTR]
  u16* Wlo = smem + 4*16*WSTR;
  const int bid = blockIdx.x;
  const int grp = bid & 7;            // dir*4 + mtile
  const int nt  = bid >> 3;
  const int dir = grp >> 2;
  const int m0  = (grp & 3) * 64;
  const int u0  = nt * 16;
  const int tid = threadIdx.x;
  const int wave = tid >> 6, lane = tid & 63;
  const int lrow = lane & 15, kblk = lane >> 4;
  const int koff = kblk * 8;
  {
    const size_t wbase = ((size_t)dir*1024 + u0) * 448;
    for (int idx = tid; idx < 4*16*448; idx += 256){
      int g = idx / (16*448);
      int r = idx - g*(16*448);
      int j = r / 448;
      int k = r - j*448;
      size_t go = wbase + ((size_t)g*256 + j)*448 + k;
      Whi[(g*16 + j)*WSTR + k] = W_hi[go];
      Wlo[(g*16 + j)*WSTR + k] = W_lo[go];
    }
  }
  const float* bias = dir ? b_eb : b_ef;
  float bg4[4];
  #pragma unroll
  for (int g=0; g<4; g++) bg4[g] = bias[g*H_ + u0 + lrow];
  __syncthreads();

  const int mrow = m0 + wave*16;
  const int arow = mrow + lrow;
  u32* hP0 = hbuf + (size_t)dir*(B_*H_);
  u32* hP1 = hbuf + (size_t)(2+dir)*(B_*H_);
  int* gbar = bar + grp*T_;
  float c_reg[4] = {0.f,0.f,0.f,0.f};

  for (int s=0; s<T_; s++){
    const int t = dir ? (T_-1-s) : s;
    f32x4 acc[4] = {};
    // ---- x part (k 0..191): independent of h -> before barrier ----
    const u32* abase = hsp32 + ((size_t)t*B_ + arow)*DSP_;
    #pragma unroll
    for (int ks=0; ks<6; ks++){
      int kb = ks*32 + koff;
      u32x8 la = *(const u32x8*)(abase + kb);
      bf16x8 ah, al;
      #pragma unroll
      for (int j=0;j<8;j++){ ah[j]=(short)(la[j]&0xFFFFu); al[j]=(short)(la[j]>>16); }
      #pragma unroll
      for (int g=0; g<4; g++){
        bf16x8 bh = *(const bf16x8*)(Whi + (g*16+lrow)*WSTR + kb);
        bf16x8 bl = *(const bf16x8*)(Wlo + (g*16+lrow)*WSTR + kb);
        acc[g] = __builtin_amdgcn_mfma_f32_16x16x32_bf16(ah, bh, acc[g], 0,0,0);
        acc[g] = __builtin_amdgcn_mfma_f32_16x16x32_bf16(ah, bl, acc[g], 0,0,0);
        acc[g] = __builtin_amdgcn_mfma_f32_16x16x32_bf16(al, bh, acc[g], 0,0,0);
      }
    }
    // ---- wait for group's h(s-1) ----
    if (s > 0){
      if (tid == 0){
        while (__hip_atomic_load(&gbar[s-1], __ATOMIC_ACQUIRE, __HIP_MEMORY_SCOPE_AGENT) < GRP_SZ)
          __builtin_amdgcn_s_sleep(1);
      }
      __syncthreads();
    }
    const u32* hin = (s & 1) ? hP1 : hP0;
    u32* hout      = (s & 1) ? hP0 : hP1;
    // ---- h part (k 192..447) ----
    const u32* hbase = hin + (size_t)arow*H_;
    #pragma unroll
    for (int ks=0; ks<8; ks++){
      int kb = ks*32 + koff;
      u32x8 la = *(const u32x8*)(hbase + kb);
      bf16x8 ah, al;
      #pragma unroll
      for (int j=0;j<8;j++){ ah[j]=(short)(la[j]&0xFFFFu); al[j]=(short)(la[j]>>16); }
      #pragma unroll
      for (int g=0; g<4; g++){
        bf16x8 bh = *(const bf16x8*)(Whi + (g*16+lrow)*WSTR + 192 + kb);
        bf16x8 bl = *(const bf16x8*)(Wlo + (g*16+lrow)*WSTR + 192 + kb);
        acc[g] = __builtin_amdgcn_mfma_f32_16x16x32_bf16(ah, bh, acc[g], 0,0,0);
        acc[g] = __builtin_amdgcn_mfma_f32_16x16x32_bf16(ah, bl, acc[g], 0,0,0);
        acc[g] = __builtin_amdgcn_mfma_f32_16x16x32_bf16(al, bh, acc[g], 0,0,0);
      }
    }
    // ---- cell (c in registers), h/eo writes ----
    #pragma unroll
    for (int r=0; r<4; r++){
      int brow = mrow + kblk*4 + r;
      float gi = acc[0][r] + bg4[0];
      float gf = acc[1][r] + bg4[1];
      float gg = acc[2][r] + bg4[2];
      float go = acc[3][r] + bg4[3];
      float cn = sigm(gf)*c_reg[r] + sigm(gi)*tanhf(gg);
      float hn = sigm(go)*tanhf(cn);
      c_reg[r] = cn;
      u32 hp = packsplit(hn);
      hout[(size_t)brow*H_ + u0 + lrow] = hp;
      __builtin_nontemporal_store(hp, &eo32[((size_t)brow*T_ + t)*512 + dir*H_ + u0 + lrow]);
    }
    if (s == T_-1) break;
    __syncthreads();
    if (tid == 0)
      __hip_atomic_fetch_add(&gbar[s], 1, __ATOMIC_RELEASE, __HIP_MEMORY_SCOPE_AGENT);
  }
}

// ---- sync-free persistent decoder: 64 blocks x 4 batch rows, all state block-local ----
__global__ __launch_bounds__(256) void dec_all(
    const u32* __restrict__ eo32, const float* __restrict__ ep,
    const float* __restrict__ Wd, const float* __restrict__ v,
    const float* __restrict__ Wo, const float* __restrict__ bo,
    const u16* __restrict__ W_hi, const u16* __restrict__ W_lo,
    const float* __restrict__ b_d, const float* __restrict__ Wx_d,
    const float* __restrict__ hd0, const float* __restrict__ cd0,
    const float* __restrict__ x, float* __restrict__ out)
{
  __shared__ __align__(32) u32 din[4][768];   // [row][col] packed: ctx(0..511) | h(512..767)
  __shared__ float hfp[4][256];
  __shared__ float cst[4][256];
  __shared__ float wsm[4][256];
  __shared__ float hwd[4][64];
  __shared__ float py4[4];
  __shared__ float bgl[1024], w0l[1024];
  const int row0 = blockIdx.x*4;
  const int tid = threadIdx.x;
  const int wave = tid>>6, lane = tid&63;

  #pragma unroll
  for (int r=0;r<4;r++){
    float h0 = hd0[(size_t)(row0+r)*H_ + tid];
    hfp[r][tid] = h0;
    cst[r][tid] = cd0[(size_t)(row0+r)*H_ + tid];
    din[r][512+tid] = packsplit(h0);
  }
  #pragma unroll
  for (int i=0;i<4;i++){
    bgl[tid+i*256] = b_d[tid+i*256];
    w0l[tid+i*256] = Wx_d[tid+i*256];
  }
  if (tid < 4){
    size_t xb = ((size_t)(row0+tid)*T_ + 255)*F_;
    py4[tid] = (x[xb] + x[xb+2])*0.5f;
  }
  __syncthreads();

  for (int s=0; s<=HOR_; s++){
    // ---- head: y_{s-1} = h_s @ Wo + bo ; py ----  (wave w -> row w)
    if (s > 0){
      float p = hfp[wave][lane]*Wo[lane] + hfp[wave][lane+64]*Wo[lane+64]
              + hfp[wave][lane+128]*Wo[lane+128] + hfp[wave][lane+192]*Wo[lane+192];
      p = wred_sum(p);
      if (lane == 0){
        float y = p + bo[0];
        out[(size_t)(row0+wave)*HOR_ + (s-1)] = y;
        py4[wave] = y;
      }
      __syncthreads();
    }
    if (s == HOR_) break;
    // ---- hWd[r][a] ----  (wave -> row, lane -> a)
    {
      float a = 0.f;
      for (int j=0;j<H_;j++) a += hfp[wave][j]*Wd[(size_t)j*A_ + lane];
      hwd[wave][lane] = a;
    }
    __syncthreads();
    // ---- scores: thread t computes all 4 rows ----
    {
      const int t = tid;
      #pragma unroll
      for (int r=0;r<4;r++){
        const float4* ep4 = (const float4*)(ep + ((size_t)(row0+r)*T_ + t)*A_);
        float sc = 0.f;
        #pragma unroll
        for (int q=0;q<16;q++){
          float4 e4 = ep4[q];
          int a0 = q*4;
          sc += tanhf(e4.x+hwd[r][a0+0])*v[a0+0];
          sc += tanhf(e4.y+hwd[r][a0+1])*v[a0+1];
          sc += tanhf(e4.z+hwd[r][a0+2])*v[a0+2];
          sc += tanhf(e4.w+hwd[r][a0+3])*v[a0+3];
        }
        wsm[r][t] = sc;
      }
    }
    __syncthreads();
    // ---- softmax per row (wave w -> row w; lane holds t = lane,+64,+128,+192) ----
    {
      const int r = wave;
      float s0=wsm[r][lane], s1=wsm[r][lane+64], s2=wsm[r][lane+128], s3=wsm[r][lane+192];
      float mx = wred_max(fmaxf(fmaxf(s0,s1),fmaxf(s2,s3)));
      float e0=expf(s0-mx), e1=expf(s1-mx), e2=expf(s2-mx), e3=expf(s3-mx);
      float inv = 1.f / wred_sum((e0+e1)+(e2+e3));
      wsm[r][lane]=e0*inv; wsm[r][lane+64]=e1*inv; wsm[r][lane+128]=e2*inv; wsm[r][lane+192]=e3*inv;
    }
    // ---- context (same wave owns same row -> no barrier needed) ----
    {
      const int r = wave;
      float cacc[8] = {0.f,0.f,0.f,0.f,0.f,0.f,0.f,0.f};
      const u32* eo = eo32 + (size_t)(row0+r)*T_*512 + lane*8;
      #pragma unroll 4
      for (int t=0;t<T_;t++){
        float wgt = wsm[r][t];
        u32x4 e0 = *(const u32x4*)(eo + (size_t)t*512);
        u32x4 e1 = *(const u32x4*)(eo + (size_t)t*512 + 4);
        #pragma unroll
        for (int j=0;j<4;j++){
          cacc[j]   += wgt*unpack2f(e0[j]);
          cacc[4+j] += wgt*unpack2f(e1[j]);
        }
      }
      #pragma unroll
      for (int j=0;j<8;j++) din[r][lane*8+j] = packsplit(cacc[j]);
    }
    __syncthreads();
    // ---- LSTM GEMM: wave w -> gate-units [w*64, w*64+64); M-tile 16 (4 real rows) ----
    {
      const int r4 = lane & 15;
      const int kblk = lane >> 4, koff = kblk*8;
      f32x4 acc[4][4] = {};    // [unit-tile][gate]
      for (int ks=0; ks<24; ks++){
        int kb = ks*32 + koff;
        bf16x8 ah, al;
        if (r4 < 4){
          u32x8 ld = *(const u32x8*)(&din[r4][kb]);
          #pragma unroll
          for (int j=0;j<8;j++){ ah[j]=(short)(ld[j]&0xFFFFu); al[j]=(short)(ld[j]>>16); }
        } else {
          #pragma unroll
          for (int j=0;j<8;j++){ ah[j]=0; al[j]=0; }
        }
        #pragma unroll
        for (int ut=0; ut<4; ut++){
          #pragma unroll
          for (int g=0; g<4; g++){
            size_t n = (size_t)(g*256 + wave*64 + ut*16 + r4)*768;
            bf16x8 bh = *(const bf16x8*)(W_hi + n + kb);
            bf16x8 bl = *(const bf16x8*)(W_lo + n + kb);
            acc[ut][g] = __builtin_amdgcn_mfma_f32_16x16x32_bf16(ah, bh, acc[ut][g], 0,0,0);
            acc[ut][g] = __builtin_amdgcn_mfma_f32_16x16x32_bf16(ah, bl, acc[ut][g], 0,0,0);
            acc[ut][g] = __builtin_amdgcn_mfma_f32_16x16x32_bf16(al, bh, acc[ut][g], 0,0,0);
          }
        }
      }
      __syncthreads();   // all waves done READING din[.][512..768] before h rewrite
      if (kblk == 0){
        #pragma unroll
        for (int ut=0; ut<4; ut++){
          int u = wave*64 + ut*16 + r4;
          #pragma unroll
          for (int r=0;r<4;r++){
            float pyr = py4[r];
            float gi = acc[ut][0][r] + bgl[u]     + pyr*w0l[u];
            float gf = acc[ut][1][r] + bgl[256+u] + pyr*w0l[256+u];
            float gg = acc[ut][2][r] + bgl[512+u] + pyr*w0l[512+u];
            float go = acc[ut][3][r] + bgl[768+u] + pyr*w0l[768+u];
            float cn = sigm(gf)*cst[r][u] + sigm(gi)*tanhf(gg);
            float hn = sigm(go)*tanhf(cn);
            cst[r][u] = cn;
            hfp[r][u] = hn;
            din[r][512+u] = packsplit(hn);
          }
        }
      }
    }
    __syncthreads();
  }
}

// ---- enc_proj: ep[bt][64] = eo @ We ----
__global__ __launch_bounds__(256) void gemm_ep(
    const u32* __restrict__ eo32, const u16* __restrict__ Wet_hi, const u16* __restrict__ Wet_lo,
    float* __restrict__ ep)
{
  const int tid = threadIdx.x, wave = tid>>6, lane = tid&63;
  const int lrow = lane&15, kblk = lane>>4, koff = kblk*8;
  const size_t arow = (size_t)blockIdx.x*64 + wave*16 + lrow;
  f32x4 acc[4] = {};
  size_t wro[4];
  #pragma unroll
  for (int nf=0; nf<4; nf++) wro[nf] = (size_t)(nf*16 + lrow)*512;
  for (int ks=0; ks<16; ks++){
    int kb = ks*32 + koff;
    u32x8 ld = *(const u32x8*)(eo32 + arow*512 + kb);
    bf16x8 ah, al;
    #pragma unroll
    for (int j=0;j<8;j++){ ah[j] = (short)(ld[j] & 0xFFFFu); al[j] = (short)(ld[j] >> 16); }
    #pragma unroll
    for (int nf=0; nf<4; nf++){
      bf16x8 bh = *(const bf16x8*)(Wet_hi + wro[nf] + kb);
      bf16x8 bl = *(const bf16x8*)(Wet_lo + wro[nf] + kb);
      acc[nf] = __builtin_amdgcn_mfma_f32_16x16x32_bf16(ah, bh, acc[nf], 0,0,0);
      acc[nf] = __builtin_amdgcn_mfma_f32_16x16x32_bf16(ah, bl, acc[nf], 0,0,0);
      acc[nf] = __builtin_amdgcn_mfma_f32_16x16x32_bf16(al, bh, acc[nf], 0,0,0);
    }
  }
  #pragma unroll
  for (int nf=0; nf<4; nf++)
    #pragma unroll
    for (int r=0; r<4; r++){
      size_t orow = (size_t)blockIdx.x*64 + wave*16 + kblk*4 + r;
      ep[orow*64 + nf*16 + lrow] = acc[nf][r];
    }
}

// ---- generic fp32 SGEMM for small init GEMMs ----
__global__ __launch_bounds__(256) void sgemm_bias(
    const float* __restrict__ A, const float* __restrict__ W,
    const float* __restrict__ bias, float* __restrict__ C,
    int M, int N, int K, int act)
{
  __shared__ float As[64][17];
  __shared__ float Ws[16][64];
  int tid = threadIdx.x;
  int tr = tid >> 4, tc = tid & 15;
  int row0 = blockIdx.y * 64, col0 = blockIdx.x * 64;
  float acc[4][4] = {};
  for (int k0 = 0; k0 < K; k0 += 16) {
    for (int i = tid; i < 64*16; i += 256) {
      int r = i >> 4, kk = i & 15;
      int gr = row0 + r, gk = k0 + kk;
      As[r][kk] = (gr < M && gk < K) ? A[(size_t)gr*K + gk] : 0.f;
    }
    for (int i = tid; i < 16*64; i += 256) {
      int r = i >> 6, c = i & 63;
      int gk = k0 + r, gc = col0 + c;
      Ws[r][c] = (gk < K && gc < N) ? W[(size_t)gk*N + gc] : 0.f;
    }
    __syncthreads();
    #pragma unroll
    for (int kk=0;kk<16;kk++){
      float a0 = As[tr*4+0][kk], a1 = As[tr*4+1][kk];
      float a2v = As[tr*4+2][kk], a3 = As[tr*4+3][kk];
      float4 b4 = *(const float4*)&Ws[kk][tc*4];
      acc[0][0]+=a0*b4.x; acc[0][1]+=a0*b4.y; acc[0][2]+=a0*b4.z; acc[0][3]+=a0*b4.w;
      acc[1][0]+=a1*b4.x; acc[1][1]+=a1*b4.y; acc[1][2]+=a1*b4.z; acc[1][3]+=a1*b4.w;
      acc[2][0]+=a2v*b4.x; acc[2][1]+=a2v*b4.y; acc[2][2]+=a2v*b4.z; acc[2][3]+=a2v*b4.w;
      acc[3][0]+=a3*b4.x; acc[3][1]+=a3*b4.y; acc[3][2]+=a3*b4.z; acc[3][3]+=a3*b4.w;
    }
    __syncthreads();
  }
  #pragma unroll
  for (int i=0;i<4;i++){
    int r = row0 + tr*4 + i; if (r >= M) continue;
    #pragma unroll
    for (int j=0;j<4;j++){
      int c = col0 + tc*4 + j; if (c >= N) continue;
      float vv = acc[i][j] + (bias ? bias[c] : 0.f);
      if (act == 1) vv = tanhf(vv);
      C[(size_t)r*N + c] = vv;
    }
  }
}

__global__ __launch_bounds__(256) void enc_mean_k(const u32* __restrict__ eo32,
                                                  float* __restrict__ em){
  __shared__ float redc[4][512];
  int b = blockIdx.x, tid = threadIdx.x;
  int wave = tid >> 6, lane = tid & 63;
  float cacc[8] = {};
  const u32* eo = eo32 + (size_t)b*T_*512 + lane*8;
  #pragma unroll 8
  for (int tt=0; tt<64; tt++){
    int t = wave*64 + tt;
    u32x4 e0 = *(const u32x4*)(eo + (size_t)t*512);
    u32x4 e1 = *(const u32x4*)(eo + (size_t)t*512 + 4);
    #pragma unroll
    for (int j=0;j<4;j++){ cacc[j] += unpack2f(e0[j]); cacc[4+j] += unpack2f(e1[j]); }
  }
  #pragma unroll
  for (int j=0;j<8;j++) redc[wave][lane*8+j] = cacc[j];
  __syncthreads();
  em[(size_t)b*512 + tid]       = (redc[0][tid]+redc[1][tid]+redc[2][tid]+redc[3][tid])*(1.f/T_);
  em[(size_t)b*512 + 256 + tid] = (redc[0][256+tid]+redc[1][256+tid]+redc[2][256+tid]+redc[3][256+tid])*(1.f/T_);
}

extern "C" void kernel_launch(void* const* d_in, const int* in_sizes, int n_in,
                              void* d_out, int out_size, void* d_ws, size_t ws_size,
                              hipStream_t stream)
{
  const float* x    = (const float*)d_in[0];
  const float* W_sp = (const float*)d_in[1];
  const float* b_sp = (const float*)d_in[2];
  const float* Wx_ef= (const float*)d_in[3];
  const float* Wh_ef= (const float*)d_in[4];
  const float* b_ef = (const float*)d_in[5];
  const float* Wx_eb= (const float*)d_in[6];
  const float* Wh_eb= (const float*)d_in[7];
  const float* b_eb = (const float*)d_in[8];
  const float* We   = (const float*)d_in[9];
  const float* Wd   = (const float*)d_in[10];
  const float* v    = (const float*)d_in[11];
  const float* Wx_d = (const float*)d_in[12];
  const float* Wh_d = (const float*)d_in[13];
  const float* b_d  = (const float*)d_in[14];
  const float* W_ih = (const float*)d_in[15];
  const float* b_ih = (const float*)d_in[16];
  const float* W_ic = (const float*)d_in[17];
  const float* b_ic = (const float*)d_in[18];
  const float* Wo   = (const float*)d_in[19];
  const float* bo   = (const float*)d_in[20];
  float* out = (float*)d_out;

  char* base = (char*)d_ws;
  auto alloc = [&](size_t bytes)->char*{
    char* p = base; base += (bytes + 255) & ~(size_t)255; return p;
  };
  u16* Wenc_hi = (u16*)alloc((size_t)2*1024*448*2);
  u16* Wenc_lo = (u16*)alloc((size_t)2*1024*448*2);
  u16* Wdec_hi = (u16*)alloc((size_t)1024*768*2);
  u16* Wdec_lo = (u16*)alloc((size_t)1024*768*2);
  u16* Wet_hi  = (u16*)alloc((size_t)64*512*2);
  u16* Wet_lo  = (u16*)alloc((size_t)64*512*2);
  u32* hsp32   = (u32*)alloc((size_t)T_*B_*DSP_*4);
  u32* hbuf    = (u32*)alloc((size_t)2*2*B_*H_*4);   // [parity][dir][b][u]
  u32* eo32    = (u32*)alloc((size_t)B_*T_*512*4);
  float* em    = (float*)alloc((size_t)B_*512*4);
  float* ep    = (float*)alloc((size_t)B_*T_*64*4);
  float* hd    = (float*)alloc((size_t)B_*H_*4);
  float* cd    = (float*)alloc((size_t)B_*H_*4);
  int* bar     = (int*)alloc((size_t)8*T_*4);        // enc counters (round-4)
  if ((size_t)(base - (char*)d_ws) > ws_size) return;

  // one-time weight conversions
  conv_w<<<dim3(1792),256,0,stream>>>(Wx_ef, Wh_ef, Wenc_hi, Wenc_lo, DSP_, 448, 1024);
  conv_w<<<dim3(1792),256,0,stream>>>(Wx_eb, Wh_eb, Wenc_hi+458752, Wenc_lo+458752, DSP_, 448, 1024);
  conv_w<<<dim3(3072),256,0,stream>>>(Wx_d+1024, Wh_d, Wdec_hi, Wdec_lo, 512, 768, 1024);
  conv_w<<<dim3(128),256,0,stream>>>(We, We, Wet_hi, Wet_lo, 512, 512, 64);

  spatial_proj<<<dim3(256),192,0,stream>>>(x, W_sp, b_sp, hsp32);

  hipMemsetAsync(hbuf, 0, (size_t)2*B_*H_*4, stream);   // parity-0 h = 0
  hipMemsetAsync(bar, 0, (size_t)8*T_*4, stream);       // enc barrier counters

  enc_scan<<<dim3(ENC_NBLK), dim3(256), 2*4*16*WSTR*2, stream>>>(
      hsp32, Wenc_hi, Wenc_lo, b_ef, b_eb, hbuf, eo32, bar);

  enc_mean_k<<<dim3(256),256,0,stream>>>(eo32, em);
  sgemm_bias<<<dim3(4,4),256,0,stream>>>(em, W_ih, b_ih, hd, B_, H_, 2*H_, 1);
  sgemm_bias<<<dim3(4,4),256,0,stream>>>(em, W_ic, b_ic, cd, B_, H_, 2*H_, 1);
  gemm_ep<<<dim3(1024),256,0,stream>>>(eo32, Wet_hi, Wet_lo, ep);

  // sync-free persistent decoder (no cross-block communication at all)
  dec_all<<<dim3(64),256,0,stream>>>(
      eo32, ep, Wd, v, Wo, bo, Wdec_hi, Wdec_lo, b_d, Wx_d, hd, cd, x, out);
}

// Round 8
// 6625.692 us; speedup vs baseline: 1.8216x; 1.8216x over previous
//
#include <hip/hip_runtime.h>
#include <cmath>

#define B_ 256
#define T_ 256
#define F_ 40
#define H_ 256
#define A_ 64
#define HOR_ 60
#define DSP_ 192
#define ENC_NBLK 128
#define GRP_SZ 16     // blocks per enc barrier group (one dir x mtile)
#define WSTR 456      // LDS weight row stride in u16 (448 + pad)

typedef unsigned short u16;
typedef unsigned int u32;
typedef __attribute__((ext_vector_type(8))) short bf16x8;
typedef __attribute__((ext_vector_type(4))) float f32x4;
typedef __attribute__((ext_vector_type(8))) u32 u32x8;
typedef __attribute__((ext_vector_type(4))) u32 u32x4;

__device__ __forceinline__ float sigm(float x){ return 1.f/(1.f+expf(-x)); }

__device__ __forceinline__ u16 f2bf(float x){
  u32 u = __float_as_uint(x);
  u32 r = (u + 0x7FFFu + ((u>>16)&1u)) >> 16;
  return (u16)r;
}
__device__ __forceinline__ float bf2f(u16 h){ return __uint_as_float(((u32)h)<<16); }
__device__ __forceinline__ u32 packsplit(float x){
  u16 hi = f2bf(x);
  u16 lo = f2bf(x - bf2f(hi));
  return (u32)hi | ((u32)lo<<16);
}
__device__ __forceinline__ float unpack2f(u32 v){
  return __uint_as_float(v<<16) + __uint_as_float(v & 0xFFFF0000u);
}

__device__ __forceinline__ float wred_sum(float v){
  #pragma unroll
  for (int o=32;o>0;o>>=1) v += __shfl_xor(v,o);
  return v;
}
__device__ __forceinline__ float wred_max(float v){
  #pragma unroll
  for (int o=32;o>0;o>>=1) v = fmaxf(v,__shfl_xor(v,o));
  return v;
}

// ---- weight conversion: dst[n][k] (hi/lo bf16) = src[k][n], src = [Wx ; Wh] ----
__global__ void conv_w(const float* __restrict__ Wx, const float* __restrict__ Wh,
                       u16* __restrict__ hi, u16* __restrict__ lo,
                       int KX, int Ktot, int N){
  int idx = blockIdx.x*256 + threadIdx.x;
  if (idx >= N*Ktot) return;
  int n = idx / Ktot, k = idx - n*Ktot;
  float w = (k < KX) ? Wx[(size_t)k*N + n] : Wh[(size_t)(k-KX)*N + n];
  u16 h = f2bf(w);
  hi[idx] = h;
  lo[idx] = f2bf(w - bf2f(h));
}

// ---- spatial projection: hsp32[t][b][192] packed = x[b][t][:40] @ W_sp + b_sp ----
__global__ __launch_bounds__(192) void spatial_proj(
    const float* __restrict__ x, const float* __restrict__ W, const float* __restrict__ bsp,
    u32* __restrict__ hsp32){
  __shared__ float Ws[40][192];
  __shared__ float xr[40];
  int t = blockIdx.x, tid = threadIdx.x;
  for (int i = tid; i < 40*192; i += 192){ int k = i/192, c = i-k*192; Ws[k][c] = W[i]; }
  float bb = bsp[tid];
  __syncthreads();
  for (int b=0; b<B_; b++){
    if (tid < 40) xr[tid] = x[((size_t)b*T_ + t)*F_ + tid];
    __syncthreads();
    float acc = bb;
    #pragma unroll
    for (int k=0;k<40;k++) acc += xr[k]*Ws[k][tid];
    hsp32[((size_t)t*B_ + b)*DSP_ + tid] = packsplit(acc);
    __syncthreads();
  }
}

// ---- persistent bidirectional encoder scan (round-4 proven; eo store now normal) ----
__global__ __launch_bounds__(256) void enc_scan(
    const u32* __restrict__ hsp32,
    const u16* __restrict__ W_hi, const u16* __restrict__ W_lo,
    const float* __restrict__ b_ef, const float* __restrict__ b_eb,
    u32* __restrict__ hbuf, u32* __restrict__ eo32, int* __restrict__ bar)
{
  extern __shared__ u16 smem[];
  u16* Whi = smem;                    // [4 gates][16 units][WSTR]
  u16* Wlo = smem + 4*16*WSTR;
  const int bid = blockIdx.x;
  const int grp = bid & 7;            // dir*4 + mtile
  const int nt  = bid >> 3;
  const int dir = grp >> 2;
  const int m0  = (grp & 3) * 64;
  const int u0  = nt * 16;
  const int tid = threadIdx.x;
  const int wave = tid >> 6, lane = tid & 63;
  const int lrow = lane & 15, kblk = lane >> 4;
  const int koff = kblk * 8;
  {
    const size_t wbase = ((size_t)dir*1024 + u0) * 448;
    for (int idx = tid; idx < 4*16*448; idx += 256){
      int g = idx / (16*448);
      int r = idx - g*(16*448);
      int j = r / 448;
      int k = r - j*448;
      size_t go = wbase + ((size_t)g*256 + j)*448 + k;
      Whi[(g*16 + j)*WSTR + k] = W_hi[go];
      Wlo[(g*16 + j)*WSTR + k] = W_lo[go];
    }
  }
  const float* bias = dir ? b_eb : b_ef;
  float bg4[4];
  #pragma unroll
  for (int g=0; g<4; g++) bg4[g] = bias[g*H_ + u0 + lrow];
  __syncthreads();

  const int mrow = m0 + wave*16;
  const int arow = mrow + lrow;
  u32* hP0 = hbuf + (size_t)dir*(B_*H_);
  u32* hP1 = hbuf + (size_t)(2+dir)*(B_*H_);
  int* gbar = bar + grp*T_;
  float c_reg[4] = {0.f,0.f,0.f,0.f};

  for (int s=0; s<T_; s++){
    const int t = dir ? (T_-1-s) : s;
    f32x4 acc[4] = {};
    // ---- x part (k 0..191): independent of h -> before barrier ----
    const u32* abase = hsp32 + ((size_t)t*B_ + arow)*DSP_;
    #pragma unroll
    for (int ks=0; ks<6; ks++){
      int kb = ks*32 + koff;
      u32x8 la = *(const u32x8*)(abase + kb);
      bf16x8 ah, al;
      #pragma unroll
      for (int j=0;j<8;j++){ ah[j]=(short)(la[j]&0xFFFFu); al[j]=(short)(la[j]>>16); }
      #pragma unroll
      for (int g=0; g<4; g++){
        bf16x8 bh = *(const bf16x8*)(Whi + (g*16+lrow)*WSTR + kb);
        bf16x8 bl = *(const bf16x8*)(Wlo + (g*16+lrow)*WSTR + kb);
        acc[g] = __builtin_amdgcn_mfma_f32_16x16x32_bf16(ah, bh, acc[g], 0,0,0);
        acc[g] = __builtin_amdgcn_mfma_f32_16x16x32_bf16(ah, bl, acc[g], 0,0,0);
        acc[g] = __builtin_amdgcn_mfma_f32_16x16x32_bf16(al, bh, acc[g], 0,0,0);
      }
    }
    // ---- wait for group's h(s-1) ----
    if (s > 0){
      if (tid == 0){
        while (__hip_atomic_load(&gbar[s-1], __ATOMIC_ACQUIRE, __HIP_MEMORY_SCOPE_AGENT) < GRP_SZ)
          __builtin_amdgcn_s_sleep(1);
      }
      __syncthreads();
    }
    const u32* hin = (s & 1) ? hP1 : hP0;
    u32* hout      = (s & 1) ? hP0 : hP1;
    // ---- h part (k 192..447) ----
    const u32* hbase = hin + (size_t)arow*H_;
    #pragma unroll
    for (int ks=0; ks<8; ks++){
      int kb = ks*32 + koff;
      u32x8 la = *(const u32x8*)(hbase + kb);
      bf16x8 ah, al;
      #pragma unroll
      for (int j=0;j<8;j++){ ah[j]=(short)(la[j]&0xFFFFu); al[j]=(short)(la[j]>>16); }
      #pragma unroll
      for (int g=0; g<4; g++){
        bf16x8 bh = *(const bf16x8*)(Whi + (g*16+lrow)*WSTR + 192 + kb);
        bf16x8 bl = *(const bf16x8*)(Wlo + (g*16+lrow)*WSTR + 192 + kb);
        acc[g] = __builtin_amdgcn_mfma_f32_16x16x32_bf16(ah, bh, acc[g], 0,0,0);
        acc[g] = __builtin_amdgcn_mfma_f32_16x16x32_bf16(ah, bl, acc[g], 0,0,0);
        acc[g] = __builtin_amdgcn_mfma_f32_16x16x32_bf16(al, bh, acc[g], 0,0,0);
      }
    }
    // ---- cell (c in registers), h/eo writes ----
    #pragma unroll
    for (int r=0; r<4; r++){
      int brow = mrow + kblk*4 + r;
      float gi = acc[0][r] + bg4[0];
      float gf = acc[1][r] + bg4[1];
      float gg = acc[2][r] + bg4[2];
      float go = acc[3][r] + bg4[3];
      float cn = sigm(gf)*c_reg[r] + sigm(gi)*tanhf(gg);
      float hn = sigm(go)*tanhf(cn);
      c_reg[r] = cn;
      u32 hp = packsplit(hn);
      hout[(size_t)brow*H_ + u0 + lrow] = hp;
      eo32[((size_t)brow*T_ + t)*512 + dir*H_ + u0 + lrow] = hp;  // normal store: seed L2/L3
    }
    if (s == T_-1) break;
    __syncthreads();
    if (tid == 0)
      __hip_atomic_fetch_add(&gbar[s], 1, __ATOMIC_RELEASE, __HIP_MEMORY_SCOPE_AGENT);
  }
}

// ---- attention step: 512 threads/block (8 waves streaming context) ----
__global__ __launch_bounds__(512) void attn_step(
    const u32* __restrict__ eo32, const float* __restrict__ ep,
    const float* __restrict__ Wd, const float* __restrict__ v,
    const float* __restrict__ Wo, const float* __restrict__ bo,
    const float* __restrict__ h_dec, u32* __restrict__ Ad32,
    float* __restrict__ py, float* __restrict__ out, int s)
{
  __shared__ float sh_h[256], sh_hwd[64], sh_v[64], sh_sc[256], sh_w[256];
  __shared__ float red8[8][64];
  __shared__ float sh_red[4], sh_red2[4];
  __shared__ float redc[8][512];
  const int b = blockIdx.x, tid = threadIdx.x;
  const int wave = tid >> 6, lane = tid & 63;
  if (tid < 256) sh_h[tid] = h_dec[b*H_ + tid];
  if (tid >= 448) sh_v[tid-448] = v[tid-448];
  __syncthreads();
  if (s > 0) {                    // y_{s-1} = h_s @ Wo + bo
    if (tid < 256){
      float p = sh_h[tid] * Wo[tid];
      p = wred_sum(p);
      if ((tid & 63) == 0) sh_red[tid>>6] = p;
    }
    __syncthreads();
    if (tid == 0){
      float y = sh_red[0]+sh_red[1]+sh_red[2]+sh_red[3] + bo[0];
      out[b*HOR_ + (s-1)] = y;
      py[b] = y;
    }
  }
  {   // hWd: wave q sums j in [q*32, q*32+32)
    float ssum = 0.f;
    for (int j=wave*32; j<wave*32+32; j++) ssum += sh_h[j]*Wd[(size_t)j*A_ + lane];
    red8[wave][lane] = ssum;
    __syncthreads();
    if (tid < 64){
      float a = 0.f;
      #pragma unroll
      for (int q=0;q<8;q++) a += red8[q][tid];
      sh_hwd[tid] = a;
    }
  }
  __syncthreads();
  {   // scores: 2 lanes per t (t = tid>>1, 32 attn dims each)
    int t = tid >> 1, aa = tid & 1;
    const float4* ep4 = (const float4*)(ep + ((size_t)(b*T_+t))*A_ + aa*32);
    float partial = 0.f;
    #pragma unroll
    for (int q=0;q<8;q++){
      float4 e4 = ep4[q];
      int a0 = aa*32 + q*4;
      partial += tanhf(e4.x + sh_hwd[a0+0]) * sh_v[a0+0];
      partial += tanhf(e4.y + sh_hwd[a0+1]) * sh_v[a0+1];
      partial += tanhf(e4.z + sh_hwd[a0+2]) * sh_v[a0+2];
      partial += tanhf(e4.w + sh_hwd[a0+3]) * sh_v[a0+3];
    }
    partial += __shfl_xor(partial, 1);
    if (aa == 0) sh_sc[t] = partial;
  }
  __syncthreads();
  if (tid < 256){                 // softmax over T (waves 0..3)
    float sc = sh_sc[tid];
    float m = wred_max(sc);
    if ((tid&63)==0) sh_red[tid>>6] = m;
    __syncthreads();
    m = fmaxf(fmaxf(sh_red[0],sh_red[1]), fmaxf(sh_red[2],sh_red[3]));
    float e = expf(sc - m);
    float su = wred_sum(e);
    if ((tid&63)==0) sh_red2[tid>>6] = su;
    __syncthreads();
    su = (sh_red2[0]+sh_red2[1])+(sh_red2[2]+sh_red2[3]);
    sh_w[tid] = e / su;
  } else { __syncthreads(); __syncthreads(); }
  __syncthreads();
  {   // context: wave w owns t in [w*32, w*32+32), 8 cols per lane
    float cacc[8] = {};
    const u32* eo = eo32 + (size_t)b*T_*512 + lane*8;
    #pragma unroll 8
    for (int tt=0; tt<32; tt++){
      int t = wave*32 + tt;
      float wgt = sh_w[t];
      u32x4 e0 = *(const u32x4*)(eo + (size_t)t*512);
      u32x4 e1 = *(const u32x4*)(eo + (size_t)t*512 + 4);
      #pragma unroll
      for (int j=0;j<4;j++){
        cacc[j]   += wgt * unpack2f(e0[j]);
        cacc[4+j] += wgt * unpack2f(e1[j]);
      }
    }
    #pragma unroll
    for (int j=0;j<8;j++) redc[wave][lane*8+j] = cacc[j];
  }
  __syncthreads();
  if (tid < 256){
    float c0 = 0.f, c1 = 0.f;
    #pragma unroll
    for (int q=0;q<8;q++){ c0 += redc[q][tid]; c1 += redc[q][256+tid]; }
    Ad32[(size_t)b*768 + tid]       = packsplit(c0);
    Ad32[(size_t)b*768 + 256 + tid] = packsplit(c1);
  }
}

// ---- decoder LSTM step (round-4 proven version) ----
__global__ __launch_bounds__(128) void dec_step_mfma(
    const u32* __restrict__ Ad32,
    const u16* __restrict__ W_hi, const u16* __restrict__ W_lo,
    const float* __restrict__ b_d, const float* __restrict__ Wx_d,
    const float* __restrict__ py,
    float* __restrict__ c_dec, float* __restrict__ h_dec,
    u32* __restrict__ AdW)
{
  const int u0 = blockIdx.x * 16;
  const int tid = threadIdx.x;
  const int wave = tid >> 6, lane = tid & 63;
  const int lrow = lane & 15, kblk = lane >> 4;
  const int u = u0 + lrow;
  const int mbase = blockIdx.y * 32 + wave * 16;
  const int koff = kblk * 8;
  size_t wro[4];
  #pragma unroll
  for (int g=0; g<4; g++) wro[g] = (size_t)(g*H_ + u) * 768;
  f32x4 acc[4] = {};
  const u32* abase = Ad32 + (size_t)(mbase + lrow)*768;
  for (int ks=0; ks<24; ks++){
    int kb = ks*32 + koff;
    u32x8 ld = *(const u32x8*)(abase + kb);
    bf16x8 ah, al;
    #pragma unroll
    for (int j=0;j<8;j++){ ah[j] = (short)(ld[j] & 0xFFFFu); al[j] = (short)(ld[j] >> 16); }
    #pragma unroll
    for (int g=0; g<4; g++){
      bf16x8 bh = *(const bf16x8*)(W_hi + wro[g] + kb);
      bf16x8 bl = *(const bf16x8*)(W_lo + wro[g] + kb);
      acc[g] = __builtin_amdgcn_mfma_f32_16x16x32_bf16(ah, bh, acc[g], 0,0,0);
      acc[g] = __builtin_amdgcn_mfma_f32_16x16x32_bf16(ah, bl, acc[g], 0,0,0);
      acc[g] = __builtin_amdgcn_mfma_f32_16x16x32_bf16(al, bh, acc[g], 0,0,0);
    }
  }
  float bg4[4], w0g[4];
  #pragma unroll
  for (int g=0;g<4;g++){ bg4[g] = b_d[g*H_ + u]; w0g[g] = Wx_d[g*H_ + u]; }
  #pragma unroll
  for (int r=0; r<4; r++){
    int bb = mbase + kblk*4 + r;
    float pyb = py[bb];
    float gi = acc[0][r] + bg4[0] + pyb*w0g[0];
    float gf = acc[1][r] + bg4[1] + pyb*w0g[1];
    float gg = acc[2][r] + bg4[2] + pyb*w0g[2];
    float go = acc[3][r] + bg4[3] + pyb*w0g[3];
    size_t ci = (size_t)bb*H_ + u;
    float cn = sigm(gf)*c_dec[ci] + sigm(gi)*tanhf(gg);
    float hn = sigm(go)*tanhf(cn);
    c_dec[ci] = cn;
    h_dec[ci] = hn;
    AdW[(size_t)bb*768 + 512 + u] = packsplit(hn);
  }
}

// ---- enc_proj: ep[bt][64] = eo @ We ----
__global__ __launch_bounds__(256) void gemm_ep(
    const u32* __restrict__ eo32, const u16* __restrict__ Wet_hi, const u16* __restrict__ Wet_lo,
    float* __restrict__ ep)
{
  const int tid = threadIdx.x, wave = tid>>6, lane = tid&63;
  const int lrow = lane&15, kblk = lane>>4, koff = kblk*8;
  const size_t arow = (size_t)blockIdx.x*64 + wave*16 + lrow;
  f32x4 acc[4] = {};
  size_t wro[4];
  #pragma unroll
  for (int nf=0; nf<4; nf++) wro[nf] = (size_t)(nf*16 + lrow)*512;
  for (int ks=0; ks<16; ks++){
    int kb = ks*32 + koff;
    u32x8 ld = *(const u32x8*)(eo32 + arow*512 + kb);
    bf16x8 ah, al;
    #pragma unroll
    for (int j=0;j<8;j++){ ah[j] = (short)(ld[j] & 0xFFFFu); al[j] = (short)(ld[j] >> 16); }
    #pragma unroll
    for (int nf=0; nf<4; nf++){
      bf16x8 bh = *(const bf16x8*)(Wet_hi + wro[nf] + kb);
      bf16x8 bl = *(const bf16x8*)(Wet_lo + wro[nf] + kb);
      acc[nf] = __builtin_amdgcn_mfma_f32_16x16x32_bf16(ah, bh, acc[nf], 0,0,0);
      acc[nf] = __builtin_amdgcn_mfma_f32_16x16x32_bf16(ah, bl, acc[nf], 0,0,0);
      acc[nf] = __builtin_amdgcn_mfma_f32_16x16x32_bf16(al, bh, acc[nf], 0,0,0);
    }
  }
  #pragma unroll
  for (int nf=0; nf<4; nf++)
    #pragma unroll
    for (int r=0; r<4; r++){
      size_t orow = (size_t)blockIdx.x*64 + wave*16 + kblk*4 + r;
      ep[orow*64 + nf*16 + lrow] = acc[nf][r];
    }
}

// ---- generic fp32 SGEMM for small init GEMMs ----
__global__ __launch_bounds__(256) void sgemm_bias(
    const float* __restrict__ A, const float* __restrict__ W,
    const float* __restrict__ bias, float* __restrict__ C,
    int M, int N, int K, int act)
{
  __shared__ float As[64][17];
  __shared__ float Ws[16][64];
  int tid = threadIdx.x;
  int tr = tid >> 4, tc = tid & 15;
  int row0 = blockIdx.y * 64, col0 = blockIdx.x * 64;
  float acc[4][4] = {};
  for (int k0 = 0; k0 < K; k0 += 16) {
    for (int i = tid; i < 64*16; i += 256) {
      int r = i >> 4, kk = i & 15;
      int gr = row0 + r, gk = k0 + kk;
      As[r][kk] = (gr < M && gk < K) ? A[(size_t)gr*K + gk] : 0.f;
    }
    for (int i = tid; i < 16*64; i += 256) {
      int r = i >> 6, c = i & 63;
      int gk = k0 + r, gc = col0 + c;
      Ws[r][c] = (gk < K && gc < N) ? W[(size_t)gk*N + gc] : 0.f;
    }
    __syncthreads();
    #pragma unroll
    for (int kk=0;kk<16;kk++){
      float a0 = As[tr*4+0][kk], a1 = As[tr*4+1][kk];
      float a2v = As[tr*4+2][kk], a3 = As[tr*4+3][kk];
      float4 b4 = *(const float4*)&Ws[kk][tc*4];
      acc[0][0]+=a0*b4.x; acc[0][1]+=a0*b4.y; acc[0][2]+=a0*b4.z; acc[0][3]+=a0*b4.w;
      acc[1][0]+=a1*b4.x; acc[1][1]+=a1*b4.y; acc[1][2]+=a1*b4.z; acc[1][3]+=a1*b4.w;
      acc[2][0]+=a2v*b4.x; acc[2][1]+=a2v*b4.y; acc[2][2]+=a2v*b4.z; acc[2][3]+=a2v*b4.w;
      acc[3][0]+=a3*b4.x; acc[3][1]+=a3*b4.y; acc[3][2]+=a3*b4.z; acc[3][3]+=a3*b4.w;
    }
    __syncthreads();
  }
  #pragma unroll
  for (int i=0;i<4;i++){
    int r = row0 + tr*4 + i; if (r >= M) continue;
    #pragma unroll
    for (int j=0;j<4;j++){
      int c = col0 + tc*4 + j; if (c >= N) continue;
      float vv = acc[i][j] + (bias ? bias[c] : 0.f);
      if (act == 1) vv = tanhf(vv);
      C[(size_t)r*N + c] = vv;
    }
  }
}

__global__ __launch_bounds__(256) void final_y(const float* __restrict__ h_dec,
    const float* __restrict__ Wo, const float* __restrict__ bo, float* __restrict__ out){
  __shared__ float sh[4];
  int b = blockIdx.x, tid = threadIdx.x;
  float p = h_dec[b*H_+tid]*Wo[tid];
  p = wred_sum(p);
  if ((tid&63)==0) sh[tid>>6]=p;
  __syncthreads();
  if (tid==0) out[b*HOR_ + HOR_-1] = sh[0]+sh[1]+sh[2]+sh[3] + bo[0];
}

__global__ __launch_bounds__(256) void enc_mean_k(const u32* __restrict__ eo32,
                                                  float* __restrict__ em){
  __shared__ float redc[4][512];
  int b = blockIdx.x, tid = threadIdx.x;
  int wave = tid >> 6, lane = tid & 63;
  float cacc[8] = {};
  const u32* eo = eo32 + (size_t)b*T_*512 + lane*8;
  #pragma unroll 8
  for (int tt=0; tt<64; tt++){
    int t = wave*64 + tt;
    u32x4 e0 = *(const u32x4*)(eo + (size_t)t*512);
    u32x4 e1 = *(const u32x4*)(eo + (size_t)t*512 + 4);
    #pragma unroll
    for (int j=0;j<4;j++){ cacc[j] += unpack2f(e0[j]); cacc[4+j] += unpack2f(e1[j]); }
  }
  #pragma unroll
  for (int j=0;j<8;j++) redc[wave][lane*8+j] = cacc[j];
  __syncthreads();
  em[(size_t)b*512 + tid]       = (redc[0][tid]+redc[1][tid]+redc[2][tid]+redc[3][tid])*(1.f/T_);
  em[(size_t)b*512 + 256 + tid] = (redc[0][256+tid]+redc[1][256+tid]+redc[2][256+tid]+redc[3][256+tid])*(1.f/T_);
}

__global__ void pack_hd(const float* __restrict__ hd, u32* __restrict__ Ad32){
  int i = blockIdx.x*256 + threadIdx.x;
  int b = i >> 8, u = i & 255;
  Ad32[(size_t)b*768 + 512 + u] = packsplit(hd[i]);
}

__global__ void py_init(const float* __restrict__ x, float* __restrict__ py){
  int b = blockIdx.x*256 + threadIdx.x;
  if (b < B_)
    py[b] = (x[(size_t)b*T_*F_ + 255*F_ + 0] +
             x[(size_t)b*T_*F_ + 255*F_ + 2]) * 0.5f;
}

extern "C" void kernel_launch(void* const* d_in, const int* in_sizes, int n_in,
                              void* d_out, int out_size, void* d_ws, size_t ws_size,
                              hipStream_t stream)
{
  const float* x    = (const float*)d_in[0];
  const float* W_sp = (const float*)d_in[1];
  const float* b_sp = (const float*)d_in[2];
  const float* Wx_ef= (const float*)d_in[3];
  const float* Wh_ef= (const float*)d_in[4];
  const float* b_ef = (const float*)d_in[5];
  const float* Wx_eb= (const float*)d_in[6];
  const float* Wh_eb= (const float*)d_in[7];
  const float* b_eb = (const float*)d_in[8];
  const float* We   = (const float*)d_in[9];
  const float* Wd   = (const float*)d_in[10];
  const float* v    = (const float*)d_in[11];
  const float* Wx_d = (const float*)d_in[12];
  const float* Wh_d = (const float*)d_in[13];
  const float* b_d  = (const float*)d_in[14];
  const float* W_ih = (const float*)d_in[15];
  const float* b_ih = (const float*)d_in[16];
  const float* W_ic = (const float*)d_in[17];
  const float* b_ic = (const float*)d_in[18];
  const float* Wo   = (const float*)d_in[19];
  const float* bo   = (const float*)d_in[20];
  float* out = (float*)d_out;

  char* base = (char*)d_ws;
  auto alloc = [&](size_t bytes)->char*{
    char* p = base; base += (bytes + 255) & ~(size_t)255; return p;
  };
  u16* Wenc_hi = (u16*)alloc((size_t)2*1024*448*2);
  u16* Wenc_lo = (u16*)alloc((size_t)2*1024*448*2);
  u16* Wdec_hi = (u16*)alloc((size_t)1024*768*2);
  u16* Wdec_lo = (u16*)alloc((size_t)1024*768*2);
  u16* Wet_hi  = (u16*)alloc((size_t)64*512*2);
  u16* Wet_lo  = (u16*)alloc((size_t)64*512*2);
  u32* hsp32   = (u32*)alloc((size_t)T_*B_*DSP_*4);
  u32* hbuf    = (u32*)alloc((size_t)2*2*B_*H_*4);   // [parity][dir][b][u]
  u32* eo32    = (u32*)alloc((size_t)B_*T_*512*4);
  float* em    = (float*)alloc((size_t)B_*512*4);
  float* ep    = (float*)alloc((size_t)B_*T_*64*4);
  float* hd    = (float*)alloc((size_t)B_*H_*4);
  float* cd    = (float*)alloc((size_t)B_*H_*4);
  u32* Ad32    = (u32*)alloc((size_t)B_*768*4);
  float* pyb   = (float*)alloc((size_t)B_*4);
  int* bar     = (int*)alloc((size_t)8*T_*4);        // enc counters (round-4)
  if ((size_t)(base - (char*)d_ws) > ws_size) return;

  // one-time weight conversions
  conv_w<<<dim3(1792),256,0,stream>>>(Wx_ef, Wh_ef, Wenc_hi, Wenc_lo, DSP_, 448, 1024);
  conv_w<<<dim3(1792),256,0,stream>>>(Wx_eb, Wh_eb, Wenc_hi+458752, Wenc_lo+458752, DSP_, 448, 1024);
  conv_w<<<dim3(3072),256,0,stream>>>(Wx_d+1024, Wh_d, Wdec_hi, Wdec_lo, 512, 768, 1024);
  conv_w<<<dim3(128),256,0,stream>>>(We, We, Wet_hi, Wet_lo, 512, 512, 64);

  spatial_proj<<<dim3(256),192,0,stream>>>(x, W_sp, b_sp, hsp32);

  hipMemsetAsync(hbuf, 0, (size_t)2*B_*H_*4, stream);   // parity-0 h = 0
  hipMemsetAsync(bar, 0, (size_t)8*T_*4, stream);       // enc barrier counters

  enc_scan<<<dim3(ENC_NBLK), dim3(256), 2*4*16*WSTR*2, stream>>>(
      hsp32, Wenc_hi, Wenc_lo, b_ef, b_eb, hbuf, eo32, bar);

  enc_mean_k<<<dim3(256),256,0,stream>>>(eo32, em);
  sgemm_bias<<<dim3(4,4),256,0,stream>>>(em, W_ih, b_ih, hd, B_, H_, 2*H_, 1);
  sgemm_bias<<<dim3(4,4),256,0,stream>>>(em, W_ic, b_ic, cd, B_, H_, 2*H_, 1);
  pack_hd<<<dim3(256),256,0,stream>>>(hd, Ad32);
  gemm_ep<<<dim3(1024),256,0,stream>>>(eo32, Wet_hi, Wet_lo, ep);
  py_init<<<dim3(1),256,0,stream>>>(x, pyb);

  // decoder: 60 steps of (attention 512-thr, LSTM) — stream-ordered, race-free
  for (int s=0; s<HOR_; s++){
    attn_step<<<dim3(256),512,0,stream>>>(eo32, ep, Wd, v, Wo, bo, hd, Ad32, pyb, out, s);
    dec_step_mfma<<<dim3(16,8),128,0,stream>>>(Ad32, Wdec_hi, Wdec_lo, b_d, Wx_d, pyb, cd, hd, Ad32);
  }
  final_y<<<dim3(256),256,0,stream>>>(hd, Wo, bo, out);
}

// Round 9
// 5919.651 us; speedup vs baseline: 2.0389x; 1.1193x over previous
//
#include <hip/hip_runtime.h>
#include <cmath>

#define B_ 256
#define T_ 256
#define F_ 40
#define H_ 256
#define A_ 64
#define HOR_ 60
#define DSP_ 192
#define ENC_NBLK 128
#define GRP_SZ 16     // blocks per enc barrier group (one dir x mtile)
#define WSTR 456      // LDS weight row stride in u16 (448 + pad)
#define FPAD 32       // flag stride in ints (128 B -> own cacheline)
#define ADLD 1024     // Ad32 row stride: ctx(512) | h_even(256) | h_odd(256)

typedef unsigned short u16;
typedef unsigned int u32;
typedef __attribute__((ext_vector_type(8))) short bf16x8;
typedef __attribute__((ext_vector_type(4))) float f32x4;
typedef __attribute__((ext_vector_type(8))) u32 u32x8;
typedef __attribute__((ext_vector_type(4))) u32 u32x4;

__device__ __forceinline__ float sigm(float x){ return 1.f/(1.f+expf(-x)); }

__device__ __forceinline__ u16 f2bf(float x){
  u32 u = __float_as_uint(x);
  u32 r = (u + 0x7FFFu + ((u>>16)&1u)) >> 16;
  return (u16)r;
}
__device__ __forceinline__ float bf2f(u16 h){ return __uint_as_float(((u32)h)<<16); }
__device__ __forceinline__ u32 packsplit(float x){
  u16 hi = f2bf(x);
  u16 lo = f2bf(x - bf2f(hi));
  return (u32)hi | ((u32)lo<<16);
}
__device__ __forceinline__ float unpack2f(u32 v){
  return __uint_as_float(v<<16) + __uint_as_float(v & 0xFFFF0000u);
}

__device__ __forceinline__ float wred_sum(float v){
  #pragma unroll
  for (int o=32;o>0;o>>=1) v += __shfl_xor(v,o);
  return v;
}
__device__ __forceinline__ float wred_max(float v){
  #pragma unroll
  for (int o=32;o>0;o>>=1) v = fmaxf(v,__shfl_xor(v,o));
  return v;
}

// Parallel-flag barrier. Arrival: release-STORE 1 to the block's own padded
// line (releaser's wbl2 flushes its own XCD L2 -> its prior writes reach the
// coherence point; no RMW convoy). Wait: lanes each ACQUIRE-poll one flag
// (every poll invalidates local caches -> no stale replay reads; this was
// round-5's bug with RELAXED polls).
__device__ __forceinline__ void flags_signal(int* f){
  __hip_atomic_store(f, 1, __ATOMIC_RELEASE, __HIP_MEMORY_SCOPE_AGENT);
}
__device__ __forceinline__ void flags_wait(const int* base, int n, int wave, int lane){
  if (wave == 0 && lane < n){
    const int* f = base + (size_t)lane*FPAD;
    while (__hip_atomic_load(f, __ATOMIC_ACQUIRE, __HIP_MEMORY_SCOPE_AGENT) == 0)
      __builtin_amdgcn_s_sleep(1);
  }
  __syncthreads();
}

// ---- weight conversion: dst[n][k] (hi/lo bf16) = src[k][n], src = [Wx ; Wh] ----
__global__ void conv_w(const float* __restrict__ Wx, const float* __restrict__ Wh,
                       u16* __restrict__ hi, u16* __restrict__ lo,
                       int KX, int Ktot, int N){
  int idx = blockIdx.x*256 + threadIdx.x;
  if (idx >= N*Ktot) return;
  int n = idx / Ktot, k = idx - n*Ktot;
  float w = (k < KX) ? Wx[(size_t)k*N + n] : Wh[(size_t)(k-KX)*N + n];
  u16 h = f2bf(w);
  hi[idx] = h;
  lo[idx] = f2bf(w - bf2f(h));
}

// ---- spatial projection: hsp32[t][b][192] packed = x[b][t][:40] @ W_sp + b_sp ----
__global__ __launch_bounds__(192) void spatial_proj(
    const float* __restrict__ x, const float* __restrict__ W, const float* __restrict__ bsp,
    u32* __restrict__ hsp32){
  __shared__ float Ws[40][192];
  __shared__ float xr[40];
  int t = blockIdx.x, tid = threadIdx.x;
  for (int i = tid; i < 40*192; i += 192){ int k = i/192, c = i-k*192; Ws[k][c] = W[i]; }
  float bb = bsp[tid];
  __syncthreads();
  for (int b=0; b<B_; b++){
    if (tid < 40) xr[tid] = x[((size_t)b*T_ + t)*F_ + tid];
    __syncthreads();
    float acc = bb;
    #pragma unroll
    for (int k=0;k<40;k++) acc += xr[k]*Ws[k][tid];
    hsp32[((size_t)t*B_ + b)*DSP_ + tid] = packsplit(acc);
    __syncthreads();
  }
}

// ---- persistent bidirectional encoder scan: flag barrier, signal-before-eo ----
__global__ __launch_bounds__(256) void enc_scan(
    const u32* __restrict__ hsp32,
    const u16* __restrict__ W_hi, const u16* __restrict__ W_lo,
    const float* __restrict__ b_ef, const float* __restrict__ b_eb,
    u32* __restrict__ hbuf, u32* __restrict__ eo32, int* __restrict__ ebar)
{
  extern __shared__ u16 smem[];
  u16* Whi = smem;                    // [4 gates][16 units][WSTR]
  u16* Wlo = smem + 4*16*WSTR;
  const int bid = blockIdx.x;
  const int grp = bid & 7;            // dir*4 + mtile
  const int nt  = bid >> 3;
  const int dir = grp >> 2;
  const int m0  = (grp & 3) * 64;
  const int u0  = nt * 16;
  const int tid = threadIdx.x;
  const int wave = tid >> 6, lane = tid & 63;
  const int lrow = lane & 15, kblk = lane >> 4;
  const int koff = kblk * 8;
  {
    const size_t wbase = ((size_t)dir*1024 + u0) * 448;
    for (int idx = tid; idx < 4*16*448; idx += 256){
      int g = idx / (16*448);
      int r = idx - g*(16*448);
      int j = r / 448;
      int k = r - j*448;
      size_t go = wbase + ((size_t)g*256 + j)*448 + k;
      Whi[(g*16 + j)*WSTR + k] = W_hi[go];
      Wlo[(g*16 + j)*WSTR + k] = W_lo[go];
    }
  }
  const float* bias = dir ? b_eb : b_ef;
  float bg4[4];
  #pragma unroll
  for (int g=0; g<4; g++) bg4[g] = bias[g*H_ + u0 + lrow];
  __syncthreads();

  const int mrow = m0 + wave*16;
  const int arow = mrow + lrow;
  u32* hP0 = hbuf + (size_t)dir*(B_*H_);
  u32* hP1 = hbuf + (size_t)(2+dir)*(B_*H_);
  float c_reg[4] = {0.f,0.f,0.f,0.f};

  for (int s=0; s<T_; s++){
    const int t = dir ? (T_-1-s) : s;
    f32x4 acc[4] = {};
    // ---- x part (k 0..191): independent of h -> before barrier ----
    const u32* abase = hsp32 + ((size_t)t*B_ + arow)*DSP_;
    #pragma unroll
    for (int ks=0; ks<6; ks++){
      int kb = ks*32 + koff;
      u32x8 la = *(const u32x8*)(abase + kb);
      bf16x8 ah, al;
      #pragma unroll
      for (int j=0;j<8;j++){ ah[j]=(short)(la[j]&0xFFFFu); al[j]=(short)(la[j]>>16); }
      #pragma unroll
      for (int g=0; g<4; g++){
        bf16x8 bh = *(const bf16x8*)(Whi + (g*16+lrow)*WSTR + kb);
        bf16x8 bl = *(const bf16x8*)(Wlo + (g*16+lrow)*WSTR + kb);
        acc[g] = __builtin_amdgcn_mfma_f32_16x16x32_bf16(ah, bh, acc[g], 0,0,0);
        acc[g] = __builtin_amdgcn_mfma_f32_16x16x32_bf16(ah, bl, acc[g], 0,0,0);
        acc[g] = __builtin_amdgcn_mfma_f32_16x16x32_bf16(al, bh, acc[g], 0,0,0);
      }
    }
    // ---- wait for group's h(s-1): 16 parallel acquire polls ----
    if (s > 0)
      flags_wait(ebar + (size_t)((grp*T_ + (s-1))*16)*FPAD, GRP_SZ, wave, lane);
    const u32* hin = (s & 1) ? hP1 : hP0;
    u32* hout      = (s & 1) ? hP0 : hP1;
    // ---- h part (k 192..447) ----
    const u32* hbase = hin + (size_t)arow*H_;
    #pragma unroll
    for (int ks=0; ks<8; ks++){
      int kb = ks*32 + koff;
      u32x8 la = *(const u32x8*)(hbase + kb);
      bf16x8 ah, al;
      #pragma unroll
      for (int j=0;j<8;j++){ ah[j]=(short)(la[j]&0xFFFFu); al[j]=(short)(la[j]>>16); }
      #pragma unroll
      for (int g=0; g<4; g++){
        bf16x8 bh = *(const bf16x8*)(Whi + (g*16+lrow)*WSTR + 192 + kb);
        bf16x8 bl = *(const bf16x8*)(Wlo + (g*16+lrow)*WSTR + 192 + kb);
        acc[g] = __builtin_amdgcn_mfma_f32_16x16x32_bf16(ah, bh, acc[g], 0,0,0);
        acc[g] = __builtin_amdgcn_mfma_f32_16x16x32_bf16(ah, bl, acc[g], 0,0,0);
        acc[g] = __builtin_amdgcn_mfma_f32_16x16x32_bf16(al, bh, acc[g], 0,0,0);
      }
    }
    // ---- cell; h store first, signal, then eo stores ----
    u32 hp4[4];
    #pragma unroll
    for (int r=0; r<4; r++){
      float gi = acc[0][r] + bg4[0];
      float gf = acc[1][r] + bg4[1];
      float gg = acc[2][r] + bg4[2];
      float go = acc[3][r] + bg4[3];
      float cn = sigm(gf)*c_reg[r] + sigm(gi)*tanhf(gg);
      float hn = sigm(go)*tanhf(cn);
      c_reg[r] = cn;
      hp4[r] = packsplit(hn);
      hout[(size_t)(mrow + kblk*4 + r)*H_ + u0 + lrow] = hp4[r];
    }
    __syncthreads();                   // drains all waves' h stores into L2
    if (s < T_-1 && tid == 0)
      flags_signal(ebar + (size_t)((grp*T_ + s)*16 + nt)*FPAD);
    #pragma unroll
    for (int r=0; r<4; r++)
      eo32[((size_t)(mrow + kblk*4 + r)*T_ + t)*512 + dir*H_ + u0 + lrow] = hp4[r];
  }
}

// ---- persistent decoder: 256 blocks, 512 thr. Block b: attn row b (phase A)
// + LSTM tile rows [16*(b>>4),+16) x units [16*(b&15),+16) (phase B).
// h double-buffered by parity (fp32 hdp + packed slot in Ad32) -> no WAR race.
__global__ __launch_bounds__(512) void dec_scan(
    const u32* __restrict__ eo32, const float* __restrict__ ep,
    const float* __restrict__ Wd, const float* __restrict__ v,
    const float* __restrict__ Wo, const float* __restrict__ bo,
    const u16* __restrict__ W_hi, const u16* __restrict__ W_lo,
    const float* __restrict__ b_d, const float* __restrict__ Wx_d,
    float* __restrict__ hdp, const float* __restrict__ cd0,
    u32* __restrict__ Ad32, float* __restrict__ py,
    float* __restrict__ out, int* __restrict__ fA, int* __restrict__ fB)
{
  __shared__ float sh_h[256], sh_hwd[64], sh_v[64], sh_sc[256], sh_w[256];
  __shared__ float red8[8][64];
  __shared__ float sh_red[4], sh_red2[4];
  __shared__ float redc[8][512];
  __shared__ float gl[4][16][16];
  const int b = blockIdx.x, tid = threadIdx.x;
  const int wave = tid >> 6, lane = tid & 63;
  const int bx = b & 15, by = b >> 4;      // phase-B role
  const int cr = tid >> 4, cu = tid & 15;  // cell role (tid<256)
  float c_reg = 0.f;
  float bg0=0,bg1=0,bg2=0,bg3=0, w00=0,w01=0,w02=0,w03=0;
  if (tid < 256){
    c_reg = cd0[(size_t)(by*16+cr)*H_ + bx*16+cu];
    int uu = bx*16 + cu;
    bg0 = b_d[uu];       bg1 = b_d[256+uu];
    bg2 = b_d[512+uu];   bg3 = b_d[768+uu];
    w00 = Wx_d[uu];      w01 = Wx_d[256+uu];
    w02 = Wx_d[512+uu];  w03 = Wx_d[768+uu];
  }
  for (int s=0; s<=HOR_; s++){
    // ---- wait h(s) of own row's group (16 phase-B arrivals) ----
    if (s > 0)
      flags_wait(fB + (size_t)(((s-1)*16 + (b>>4))*16)*FPAD, 16, wave, lane);
    const float* hsrc = hdp + (size_t)(s&1)*B_*H_;
    if (tid < 256) sh_h[tid] = hsrc[(size_t)b*H_ + tid];
    if (tid >= 448) sh_v[tid-448] = v[tid-448];
    __syncthreads();
    if (s > 0){                          // head: y_{s-1}, py
      if (tid < 256){
        float p = sh_h[tid] * Wo[tid];
        p = wred_sum(p);
        if ((tid & 63) == 0) sh_red[tid>>6] = p;
      }
      __syncthreads();
      if (tid == 0){
        float y = sh_red[0]+sh_red[1]+sh_red[2]+sh_red[3] + bo[0];
        out[b*HOR_ + (s-1)] = y;
        py[b] = y;
      }
    }
    if (s == HOR_) break;
    {   // hWd
      float ssum = 0.f;
      for (int j=wave*32; j<wave*32+32; j++) ssum += sh_h[j]*Wd[(size_t)j*A_ + lane];
      red8[wave][lane] = ssum;
      __syncthreads();
      if (tid < 64){
        float a = 0.f;
        #pragma unroll
        for (int q=0;q<8;q++) a += red8[q][tid];
        sh_hwd[tid] = a;
      }
    }
    __syncthreads();
    {   // scores: 2 lanes per t
      int t = tid >> 1, aa = tid & 1;
      const float4* ep4 = (const float4*)(ep + ((size_t)(b*T_+t))*A_ + aa*32);
      float partial = 0.f;
      #pragma unroll
      for (int q=0;q<8;q++){
        float4 e4 = ep4[q];
        int a0 = aa*32 + q*4;
        partial += tanhf(e4.x + sh_hwd[a0+0]) * sh_v[a0+0];
        partial += tanhf(e4.y + sh_hwd[a0+1]) * sh_v[a0+1];
        partial += tanhf(e4.z + sh_hwd[a0+2]) * sh_v[a0+2];
        partial += tanhf(e4.w + sh_hwd[a0+3]) * sh_v[a0+3];
      }
      partial += __shfl_xor(partial, 1);
      if (aa == 0) sh_sc[t] = partial;
    }
    __syncthreads();
    if (tid < 256){                      // softmax over T
      float sc = sh_sc[tid];
      float m = wred_max(sc);
      if ((tid&63)==0) sh_red[tid>>6] = m;
      __syncthreads();
      m = fmaxf(fmaxf(sh_red[0],sh_red[1]), fmaxf(sh_red[2],sh_red[3]));
      float e = expf(sc - m);
      float su = wred_sum(e);
      if ((tid&63)==0) sh_red2[tid>>6] = su;
      __syncthreads();
      su = (sh_red2[0]+sh_red2[1])+(sh_red2[2]+sh_red2[3]);
      sh_w[tid] = e / su;
    } else { __syncthreads(); __syncthreads(); }
    __syncthreads();
    {   // context: wave w owns t in [w*32,+32), 8 cols per lane
      float cacc[8] = {};
      const u32* eo = eo32 + (size_t)b*T_*512 + lane*8;
      #pragma unroll 8
      for (int tt=0; tt<32; tt++){
        int t = wave*32 + tt;
        float wgt = sh_w[t];
        u32x4 e0 = *(const u32x4*)(eo + (size_t)t*512);
        u32x4 e1 = *(const u32x4*)(eo + (size_t)t*512 + 4);
        #pragma unroll
        for (int j=0;j<4;j++){
          cacc[j]   += wgt * unpack2f(e0[j]);
          cacc[4+j] += wgt * unpack2f(e1[j]);
        }
      }
      #pragma unroll
      for (int j=0;j<8;j++) redc[wave][lane*8+j] = cacc[j];
    }
    __syncthreads();
    if (tid < 256){
      float c0 = 0.f, c1 = 0.f;
      #pragma unroll
      for (int q=0;q<8;q++){ c0 += redc[q][tid]; c1 += redc[q][256+tid]; }
      Ad32[(size_t)b*ADLD + tid]       = packsplit(c0);
      Ad32[(size_t)b*ADLD + 256 + tid] = packsplit(c1);
    }
    __syncthreads();                     // drain ctx/py/out stores
    if (tid == 0)
      flags_signal(fA + (size_t)((s*16 + (b>>4))*16 + (b&15))*FPAD);
    // ---- phase B: wait own tile's 16 row arrivals, GEMM, cell ----
    flags_wait(fA + (size_t)((s*16 + by)*16)*FPAD, 16, wave, lane);
    const int par = s & 1;
    if (wave < 4){
      const int g = wave;
      const int r16 = lane & 15, kb4 = lane >> 4;
      f32x4 acc = {0.f,0.f,0.f,0.f};
      const u32* ar = Ad32 + (size_t)(by*16 + r16)*ADLD;
      const u16* WH = W_hi + (size_t)(g*256 + bx*16 + r16)*768;
      const u16* WL = W_lo + (size_t)(g*256 + bx*16 + r16)*768;
      for (int ks=0; ks<24; ks++){
        int kb = ks*32 + kb4*8;
        int kp = (kb < 512) ? kb : (kb + (par<<8));   // parity slot for h
        u32x8 ld = *(const u32x8*)(ar + kp);
        bf16x8 ah, al;
        #pragma unroll
        for (int j=0;j<8;j++){ ah[j]=(short)(ld[j]&0xFFFFu); al[j]=(short)(ld[j]>>16); }
        bf16x8 bh = *(const bf16x8*)(WH + kb);
        bf16x8 bl = *(const bf16x8*)(WL + kb);
        acc = __builtin_amdgcn_mfma_f32_16x16x32_bf16(ah, bh, acc, 0,0,0);
        acc = __builtin_amdgcn_mfma_f32_16x16x32_bf16(ah, bl, acc, 0,0,0);
        acc = __builtin_amdgcn_mfma_f32_16x16x32_bf16(al, bh, acc, 0,0,0);
      }
      #pragma unroll
      for (int vv=0; vv<4; vv++) gl[g][kb4*4+vv][r16] = acc[vv];
    }
    __syncthreads();
    if (tid < 256){                      // cell: thread (cr,cu), c in register
      float pyr = py[by*16 + cr];
      float gi = gl[0][cr][cu] + bg0 + pyr*w00;
      float gf = gl[1][cr][cu] + bg1 + pyr*w01;
      float gg = gl[2][cr][cu] + bg2 + pyr*w02;
      float go = gl[3][cr][cu] + bg3 + pyr*w03;
      float cn = sigm(gf)*c_reg + sigm(gi)*tanhf(gg);
      float hn = sigm(go)*tanhf(cn);
      c_reg = cn;
      size_t ridx = (size_t)(by*16+cr)*H_ + bx*16+cu;
      hdp[(size_t)((s+1)&1)*B_*H_ + ridx] = hn;
      Ad32[(size_t)(by*16+cr)*ADLD + 512 + (((s+1)&1)<<8) + bx*16+cu] = packsplit(hn);
    }
    __syncthreads();                     // drain h stores
    if (tid == 0)
      flags_signal(fB + (size_t)((s*16 + by)*16 + bx)*FPAD);
  }
}

// ---- enc_proj: ep[bt][64] = eo @ We ----
__global__ __launch_bounds__(256) void gemm_ep(
    const u32* __restrict__ eo32, const u16* __restrict__ Wet_hi, const u16* __restrict__ Wet_lo,
    float* __restrict__ ep)
{
  const int tid = threadIdx.x, wave = tid>>6, lane = tid&63;
  const int lrow = lane&15, kblk = lane>>4, koff = kblk*8;
  const size_t arow = (size_t)blockIdx.x*64 + wave*16 + lrow;
  f32x4 acc[4] = {};
  size_t wro[4];
  #pragma unroll
  for (int nf=0; nf<4; nf++) wro[nf] = (size_t)(nf*16 + lrow)*512;
  for (int ks=0; ks<16; ks++){
    int kb = ks*32 + koff;
    u32x8 ld = *(const u32x8*)(eo32 + arow*512 + kb);
    bf16x8 ah, al;
    #pragma unroll
    for (int j=0;j<8;j++){ ah[j] = (short)(ld[j] & 0xFFFFu); al[j] = (short)(ld[j] >> 16); }
    #pragma unroll
    for (int nf=0; nf<4; nf++){
      bf16x8 bh = *(const bf16x8*)(Wet_hi + wro[nf] + kb);
      bf16x8 bl = *(const bf16x8*)(Wet_lo + wro[nf] + kb);
      acc[nf] = __builtin_amdgcn_mfma_f32_16x16x32_bf16(ah, bh, acc[nf], 0,0,0);
      acc[nf] = __builtin_amdgcn_mfma_f32_16x16x32_bf16(ah, bl, acc[nf], 0,0,0);
      acc[nf] = __builtin_amdgcn_mfma_f32_16x16x32_bf16(al, bh, acc[nf], 0,0,0);
    }
  }
  #pragma unroll
  for (int nf=0; nf<4; nf++)
    #pragma unroll
    for (int r=0; r<4; r++){
      size_t orow = (size_t)blockIdx.x*64 + wave*16 + kblk*4 + r;
      ep[orow*64 + nf*16 + lrow] = acc[nf][r];
    }
}

// ---- generic fp32 SGEMM for small init GEMMs ----
__global__ __launch_bounds__(256) void sgemm_bias(
    const float* __restrict__ A, const float* __restrict__ W,
    const float* __restrict__ bias, float* __restrict__ C,
    int M, int N, int K, int act)
{
  __shared__ float As[64][17];
  __shared__ float Ws[16][64];
  int tid = threadIdx.x;
  int tr = tid >> 4, tc = tid & 15;
  int row0 = blockIdx.y * 64, col0 = blockIdx.x * 64;
  float acc[4][4] = {};
  for (int k0 = 0; k0 < K; k0 += 16) {
    for (int i = tid; i < 64*16; i += 256) {
      int r = i >> 4, kk = i & 15;
      int gr = row0 + r, gk = k0 + kk;
      As[r][kk] = (gr < M && gk < K) ? A[(size_t)gr*K + gk] : 0.f;
    }
    for (int i = tid; i < 16*64; i += 256) {
      int r = i >> 6, c = i & 63;
      int gk = k0 + r, gc = col0 + c;
      Ws[r][c] = (gk < K && gc < N) ? W[(size_t)gk*N + gc] : 0.f;
    }
    __syncthreads();
    #pragma unroll
    for (int kk=0;kk<16;kk++){
      float a0 = As[tr*4+0][kk], a1 = As[tr*4+1][kk];
      float a2v = As[tr*4+2][kk], a3 = As[tr*4+3][kk];
      float4 b4 = *(const float4*)&Ws[kk][tc*4];
      acc[0][0]+=a0*b4.x; acc[0][1]+=a0*b4.y; acc[0][2]+=a0*b4.z; acc[0][3]+=a0*b4.w;
      acc[1][0]+=a1*b4.x; acc[1][1]+=a1*b4.y; acc[1][2]+=a1*b4.z; acc[1][3]+=a1*b4.w;
      acc[2][0]+=a2v*b4.x; acc[2][1]+=a2v*b4.y; acc[2][2]+=a2v*b4.z; acc[2][3]+=a2v*b4.w;
      acc[3][0]+=a3*b4.x; acc[3][1]+=a3*b4.y; acc[3][2]+=a3*b4.z; acc[3][3]+=a3*b4.w;
    }
    __syncthreads();
  }
  #pragma unroll
  for (int i=0;i<4;i++){
    int r = row0 + tr*4 + i; if (r >= M) continue;
    #pragma unroll
    for (int j=0;j<4;j++){
      int c = col0 + tc*4 + j; if (c >= N) continue;
      float vv = acc[i][j] + (bias ? bias[c] : 0.f);
      if (act == 1) vv = tanhf(vv);
      C[(size_t)r*N + c] = vv;
    }
  }
}

__global__ __launch_bounds__(256) void enc_mean_k(const u32* __restrict__ eo32,
                                                  float* __restrict__ em){
  __shared__ float redc[4][512];
  int b = blockIdx.x, tid = threadIdx.x;
  int wave = tid >> 6, lane = tid & 63;
  float cacc[8] = {};
  const u32* eo = eo32 + (size_t)b*T_*512 + lane*8;
  #pragma unroll 8
  for (int tt=0; tt<64; tt++){
    int t = wave*64 + tt;
    u32x4 e0 = *(const u32x4*)(eo + (size_t)t*512);
    u32x4 e1 = *(const u32x4*)(eo + (size_t)t*512 + 4);
    #pragma unroll
    for (int j=0;j<4;j++){ cacc[j] += unpack2f(e0[j]); cacc[4+j] += unpack2f(e1[j]); }
  }
  #pragma unroll
  for (int j=0;j<8;j++) redc[wave][lane*8+j] = cacc[j];
  __syncthreads();
  em[(size_t)b*512 + tid]       = (redc[0][tid]+redc[1][tid]+redc[2][tid]+redc[3][tid])*(1.f/T_);
  em[(size_t)b*512 + 256 + tid] = (redc[0][256+tid]+redc[1][256+tid]+redc[2][256+tid]+redc[3][256+tid])*(1.f/T_);
}

// hd -> hdp slot 0 (fp32) + Ad32 packed slot 0
__global__ void pack_hd(const float* __restrict__ hd, u32* __restrict__ Ad32,
                        float* __restrict__ hdp){
  int i = blockIdx.x*256 + threadIdx.x;
  int b = i >> 8, u = i & 255;
  float h0 = hd[i];
  hdp[i] = h0;
  Ad32[(size_t)b*ADLD + 512 + u] = packsplit(h0);
}

__global__ void py_init(const float* __restrict__ x, float* __restrict__ py){
  int b = blockIdx.x*256 + threadIdx.x;
  if (b < B_)
    py[b] = (x[(size_t)b*T_*F_ + 255*F_ + 0] +
             x[(size_t)b*T_*F_ + 255*F_ + 2]) * 0.5f;
}

extern "C" void kernel_launch(void* const* d_in, const int* in_sizes, int n_in,
                              void* d_out, int out_size, void* d_ws, size_t ws_size,
                              hipStream_t stream)
{
  const float* x    = (const float*)d_in[0];
  const float* W_sp = (const float*)d_in[1];
  const float* b_sp = (const float*)d_in[2];
  const float* Wx_ef= (const float*)d_in[3];
  const float* Wh_ef= (const float*)d_in[4];
  const float* b_ef = (const float*)d_in[5];
  const float* Wx_eb= (const float*)d_in[6];
  const float* Wh_eb= (const float*)d_in[7];
  const float* b_eb = (const float*)d_in[8];
  const float* We   = (const float*)d_in[9];
  const float* Wd   = (const float*)d_in[10];
  const float* v    = (const float*)d_in[11];
  const float* Wx_d = (const float*)d_in[12];
  const float* Wh_d = (const float*)d_in[13];
  const float* b_d  = (const float*)d_in[14];
  const float* W_ih = (const float*)d_in[15];
  const float* b_ih = (const float*)d_in[16];
  const float* W_ic = (const float*)d_in[17];
  const float* b_ic = (const float*)d_in[18];
  const float* Wo   = (const float*)d_in[19];
  const float* bo   = (const float*)d_in[20];
  float* out = (float*)d_out;

  char* base = (char*)d_ws;
  auto alloc = [&](size_t bytes)->char*{
    char* p = base; base += (bytes + 255) & ~(size_t)255; return p;
  };
  u16* Wenc_hi = (u16*)alloc((size_t)2*1024*448*2);
  u16* Wenc_lo = (u16*)alloc((size_t)2*1024*448*2);
  u16* Wdec_hi = (u16*)alloc((size_t)1024*768*2);
  u16* Wdec_lo = (u16*)alloc((size_t)1024*768*2);
  u16* Wet_hi  = (u16*)alloc((size_t)64*512*2);
  u16* Wet_lo  = (u16*)alloc((size_t)64*512*2);
  u32* hsp32   = (u32*)alloc((size_t)T_*B_*DSP_*4);
  u32* hbuf    = (u32*)alloc((size_t)2*2*B_*H_*4);   // [parity][dir][b][u]
  u32* eo32    = (u32*)alloc((size_t)B_*T_*512*4);
  float* em    = (float*)alloc((size_t)B_*512*4);
  float* ep    = (float*)alloc((size_t)B_*T_*64*4);
  float* hd    = (float*)alloc((size_t)B_*H_*4);
  float* cd    = (float*)alloc((size_t)B_*H_*4);
  float* hdp   = (float*)alloc((size_t)2*B_*H_*4);   // parity h (fp32)
  u32* Ad32    = (u32*)alloc((size_t)B_*ADLD*4);
  float* pyb   = (float*)alloc((size_t)B_*4);
  int* ebar    = (int*)alloc((size_t)8*T_*16*FPAD*4);
  int* fA      = (int*)alloc((size_t)HOR_*16*16*FPAD*4);
  int* fB      = (int*)alloc((size_t)HOR_*16*16*FPAD*4);
  if ((size_t)(base - (char*)d_ws) > ws_size) return;

  // one-time weight conversions
  conv_w<<<dim3(1792),256,0,stream>>>(Wx_ef, Wh_ef, Wenc_hi, Wenc_lo, DSP_, 448, 1024);
  conv_w<<<dim3(1792),256,0,stream>>>(Wx_eb, Wh_eb, Wenc_hi+458752, Wenc_lo+458752, DSP_, 448, 1024);
  conv_w<<<dim3(3072),256,0,stream>>>(Wx_d+1024, Wh_d, Wdec_hi, Wdec_lo, 512, 768, 1024);
  conv_w<<<dim3(128),256,0,stream>>>(We, We, Wet_hi, Wet_lo, 512, 512, 64);

  spatial_proj<<<dim3(256),192,0,stream>>>(x, W_sp, b_sp, hsp32);

  hipMemsetAsync(hbuf, 0, (size_t)2*B_*H_*4, stream);            // parity-0 h = 0
  hipMemsetAsync(ebar, 0, (size_t)8*T_*16*FPAD*4, stream);       // enc flags
  hipMemsetAsync(fA, 0, (size_t)HOR_*16*16*FPAD*4, stream);      // dec flags
  hipMemsetAsync(fB, 0, (size_t)HOR_*16*16*FPAD*4, stream);

  enc_scan<<<dim3(ENC_NBLK), dim3(256), 2*4*16*WSTR*2, stream>>>(
      hsp32, Wenc_hi, Wenc_lo, b_ef, b_eb, hbuf, eo32, ebar);

  enc_mean_k<<<dim3(256),256,0,stream>>>(eo32, em);
  sgemm_bias<<<dim3(4,4),256,0,stream>>>(em, W_ih, b_ih, hd, B_, H_, 2*H_, 1);
  sgemm_bias<<<dim3(4,4),256,0,stream>>>(em, W_ic, b_ic, cd, B_, H_, 2*H_, 1);
  pack_hd<<<dim3(256),256,0,stream>>>(hd, Ad32, hdp);
  gemm_ep<<<dim3(1024),256,0,stream>>>(eo32, Wet_hi, Wet_lo, ep);
  py_init<<<dim3(1),256,0,stream>>>(x, pyb);

  dec_scan<<<dim3(256),512,0,stream>>>(
      eo32, ep, Wd, v, Wo, bo, Wdec_hi, Wdec_lo, b_d, Wx_d,
      hdp, cd, Ad32, pyb, out, fA, fB);
}

// Round 10
// 5767.493 us; speedup vs baseline: 2.0927x; 1.0264x over previous
//
#include <hip/hip_runtime.h>
#include <cmath>

#define B_ 256
#define T_ 256
#define F_ 40
#define H_ 256
#define A_ 64
#define HOR_ 60
#define DSP_ 192
#define ENC_NBLK 128
#define GRP_SZ 16     // blocks per enc barrier group (one dir x mtile)
#define WSTR 456      // LDS weight row stride in u16 (448 + pad)
#define FPAD 32       // counter stride in ints (128 B -> own cacheline)
#define ADLD 1024     // Ad32 row stride: ctx(512) | h_even(256) | h_odd(256)

typedef unsigned short u16;
typedef unsigned int u32;
typedef __attribute__((ext_vector_type(8))) short bf16x8;
typedef __attribute__((ext_vector_type(4))) float f32x4;
typedef __attribute__((ext_vector_type(8))) u32 u32x8;
typedef __attribute__((ext_vector_type(4))) u32 u32x4;

__device__ __forceinline__ float sigm(float x){ return 1.f/(1.f+expf(-x)); }

__device__ __forceinline__ u16 f2bf(float x){
  u32 u = __float_as_uint(x);
  u32 r = (u + 0x7FFFu + ((u>>16)&1u)) >> 16;
  return (u16)r;
}
__device__ __forceinline__ float bf2f(u16 h){ return __uint_as_float(((u32)h)<<16); }
__device__ __forceinline__ u32 packsplit(float x){
  u16 hi = f2bf(x);
  u16 lo = f2bf(x - bf2f(hi));
  return (u32)hi | ((u32)lo<<16);
}
__device__ __forceinline__ float unpack2f(u32 v){
  return __uint_as_float(v<<16) + __uint_as_float(v & 0xFFFF0000u);
}

__device__ __forceinline__ float wred_sum(float v){
  #pragma unroll
  for (int o=32;o>0;o>>=1) v += __shfl_xor(v,o);
  return v;
}
__device__ __forceinline__ float wred_max(float v){
  #pragma unroll
  for (int o=32;o>0;o>>=1) v = fmaxf(v,__shfl_xor(v,o));
  return v;
}

// PROVEN barrier primitive (r4/r8, replay-stable AND faster than parallel
// flags per r9 measurement): arrival = RELEASE fetch_add; wait = tid0
// ACQUIRE-spin (every poll invalidates) + syncthreads.
__device__ __forceinline__ void cnt_signal(int* c){
  __hip_atomic_fetch_add(c, 1, __ATOMIC_RELEASE, __HIP_MEMORY_SCOPE_AGENT);
}
__device__ __forceinline__ void cnt_wait(const int* c, int n, int tid){
  if (tid == 0){
    while (__hip_atomic_load(c, __ATOMIC_ACQUIRE, __HIP_MEMORY_SCOPE_AGENT) < n)
      __builtin_amdgcn_s_sleep(1);
  }
  __syncthreads();
}

// ---- weight conversion: dst[n][k] (hi/lo bf16) = src[k][n], src = [Wx ; Wh] ----
__global__ void conv_w(const float* __restrict__ Wx, const float* __restrict__ Wh,
                       u16* __restrict__ hi, u16* __restrict__ lo,
                       int KX, int Ktot, int N){
  int idx = blockIdx.x*256 + threadIdx.x;
  if (idx >= N*Ktot) return;
  int n = idx / Ktot, k = idx - n*Ktot;
  float w = (k < KX) ? Wx[(size_t)k*N + n] : Wh[(size_t)(k-KX)*N + n];
  u16 h = f2bf(w);
  hi[idx] = h;
  lo[idx] = f2bf(w - bf2f(h));
}

// ---- spatial projection: hsp32[t][b][192] packed = x[b][t][:40] @ W_sp + b_sp ----
__global__ __launch_bounds__(192) void spatial_proj(
    const float* __restrict__ x, const float* __restrict__ W, const float* __restrict__ bsp,
    u32* __restrict__ hsp32){
  __shared__ float Ws[40][192];
  __shared__ float xr[40];
  int t = blockIdx.x, tid = threadIdx.x;
  for (int i = tid; i < 40*192; i += 192){ int k = i/192, c = i-k*192; Ws[k][c] = W[i]; }
  float bb = bsp[tid];
  __syncthreads();
  for (int b=0; b<B_; b++){
    if (tid < 40) xr[tid] = x[((size_t)b*T_ + t)*F_ + tid];
    __syncthreads();
    float acc = bb;
    #pragma unroll
    for (int k=0;k<40;k++) acc += xr[k]*Ws[k][tid];
    hsp32[((size_t)t*B_ + b)*DSP_ + tid] = packsplit(acc);
    __syncthreads();
  }
}

// ---- persistent bidirectional encoder scan (r8 proven version, verbatim) ----
__global__ __launch_bounds__(256) void enc_scan(
    const u32* __restrict__ hsp32,
    const u16* __restrict__ W_hi, const u16* __restrict__ W_lo,
    const float* __restrict__ b_ef, const float* __restrict__ b_eb,
    u32* __restrict__ hbuf, u32* __restrict__ eo32, int* __restrict__ bar)
{
  extern __shared__ u16 smem[];
  u16* Whi = smem;                    // [4 gates][16 units][WSTR]
  u16* Wlo = smem + 4*16*WSTR;
  const int bid = blockIdx.x;
  const int grp = bid & 7;            // dir*4 + mtile
  const int nt  = bid >> 3;
  const int dir = grp >> 2;
  const int m0  = (grp & 3) * 64;
  const int u0  = nt * 16;
  const int tid = threadIdx.x;
  const int wave = tid >> 6, lane = tid & 63;
  const int lrow = lane & 15, kblk = lane >> 4;
  const int koff = kblk * 8;
  {
    const size_t wbase = ((size_t)dir*1024 + u0) * 448;
    for (int idx = tid; idx < 4*16*448; idx += 256){
      int g = idx / (16*448);
      int r = idx - g*(16*448);
      int j = r / 448;
      int k = r - j*448;
      size_t go = wbase + ((size_t)g*256 + j)*448 + k;
      Whi[(g*16 + j)*WSTR + k] = W_hi[go];
      Wlo[(g*16 + j)*WSTR + k] = W_lo[go];
    }
  }
  const float* bias = dir ? b_eb : b_ef;
  float bg4[4];
  #pragma unroll
  for (int g=0; g<4; g++) bg4[g] = bias[g*H_ + u0 + lrow];
  __syncthreads();

  const int mrow = m0 + wave*16;
  const int arow = mrow + lrow;
  u32* hP0 = hbuf + (size_t)dir*(B_*H_);
  u32* hP1 = hbuf + (size_t)(2+dir)*(B_*H_);
  int* gbar = bar + grp*T_;
  float c_reg[4] = {0.f,0.f,0.f,0.f};

  for (int s=0; s<T_; s++){
    const int t = dir ? (T_-1-s) : s;
    f32x4 acc[4] = {};
    // ---- x part (k 0..191): independent of h -> before barrier ----
    const u32* abase = hsp32 + ((size_t)t*B_ + arow)*DSP_;
    #pragma unroll
    for (int ks=0; ks<6; ks++){
      int kb = ks*32 + koff;
      u32x8 la = *(const u32x8*)(abase + kb);
      bf16x8 ah, al;
      #pragma unroll
      for (int j=0;j<8;j++){ ah[j]=(short)(la[j]&0xFFFFu); al[j]=(short)(la[j]>>16); }
      #pragma unroll
      for (int g=0; g<4; g++){
        bf16x8 bh = *(const bf16x8*)(Whi + (g*16+lrow)*WSTR + kb);
        bf16x8 bl = *(const bf16x8*)(Wlo + (g*16+lrow)*WSTR + kb);
        acc[g] = __builtin_amdgcn_mfma_f32_16x16x32_bf16(ah, bh, acc[g], 0,0,0);
        acc[g] = __builtin_amdgcn_mfma_f32_16x16x32_bf16(ah, bl, acc[g], 0,0,0);
        acc[g] = __builtin_amdgcn_mfma_f32_16x16x32_bf16(al, bh, acc[g], 0,0,0);
      }
    }
    // ---- wait for group's h(s-1) ----
    if (s > 0){
      if (tid == 0){
        while (__hip_atomic_load(&gbar[s-1], __ATOMIC_ACQUIRE, __HIP_MEMORY_SCOPE_AGENT) < GRP_SZ)
          __builtin_amdgcn_s_sleep(1);
      }
      __syncthreads();
    }
    const u32* hin = (s & 1) ? hP1 : hP0;
    u32* hout      = (s & 1) ? hP0 : hP1;
    // ---- h part (k 192..447) ----
    const u32* hbase = hin + (size_t)arow*H_;
    #pragma unroll
    for (int ks=0; ks<8; ks++){
      int kb = ks*32 + koff;
      u32x8 la = *(const u32x8*)(hbase + kb);
      bf16x8 ah, al;
      #pragma unroll
      for (int j=0;j<8;j++){ ah[j]=(short)(la[j]&0xFFFFu); al[j]=(short)(la[j]>>16); }
      #pragma unroll
      for (int g=0; g<4; g++){
        bf16x8 bh = *(const bf16x8*)(Whi + (g*16+lrow)*WSTR + 192 + kb);
        bf16x8 bl = *(const bf16x8*)(Wlo + (g*16+lrow)*WSTR + 192 + kb);
        acc[g] = __builtin_amdgcn_mfma_f32_16x16x32_bf16(ah, bh, acc[g], 0,0,0);
        acc[g] = __builtin_amdgcn_mfma_f32_16x16x32_bf16(ah, bl, acc[g], 0,0,0);
        acc[g] = __builtin_amdgcn_mfma_f32_16x16x32_bf16(al, bh, acc[g], 0,0,0);
      }
    }
    // ---- cell (c in registers), h/eo writes ----
    #pragma unroll
    for (int r=0; r<4; r++){
      int brow = mrow + kblk*4 + r;
      float gi = acc[0][r] + bg4[0];
      float gf = acc[1][r] + bg4[1];
      float gg = acc[2][r] + bg4[2];
      float go = acc[3][r] + bg4[3];
      float cn = sigm(gf)*c_reg[r] + sigm(gi)*tanhf(gg);
      float hn = sigm(go)*tanhf(cn);
      c_reg[r] = cn;
      u32 hp = packsplit(hn);
      hout[(size_t)brow*H_ + u0 + lrow] = hp;
      eo32[((size_t)brow*T_ + t)*512 + dir*H_ + u0 + lrow] = hp;  // normal store: seed L2/L3
    }
    if (s == T_-1) break;
    __syncthreads();
    if (tid == 0)
      __hip_atomic_fetch_add(&gbar[s], 1, __ATOMIC_RELEASE, __HIP_MEMORY_SCOPE_AGENT);
  }
}

// ---- persistent decoder with self-contained prologue ----
// 256 blocks x 512 thr. Prologue (block-local): ep rows via MFMA, enc-mean,
// dec_h/dec_c GEMV+tanh, py. Loop: phase A attn (row b), phase B LSTM tile
// (rows 16*(b>>4).., units 16*(b&15)..). h parity-double-buffered.
__global__ __launch_bounds__(512) void dec_scan(
    const u32* __restrict__ eo32,
    const u16* __restrict__ Wet_hi, const u16* __restrict__ Wet_lo,
    const float* __restrict__ W_ih, const float* __restrict__ b_ih,
    const float* __restrict__ W_ic, const float* __restrict__ b_ic,
    const float* __restrict__ x, float* __restrict__ ep,
    const float* __restrict__ Wd, const float* __restrict__ v,
    const float* __restrict__ Wo, const float* __restrict__ bo,
    const u16* __restrict__ W_hi, const u16* __restrict__ W_lo,
    const float* __restrict__ b_d, const float* __restrict__ Wx_d,
    float* __restrict__ hdp, float* __restrict__ cd,
    u32* __restrict__ Ad32, float* __restrict__ py,
    float* __restrict__ out, int* __restrict__ cntA, int* __restrict__ cntB)
{
  __shared__ float sh_h[256], sh_hwd[64], sh_v[64], sh_sc[256], sh_w[256];
  __shared__ float red8[8][64];
  __shared__ float sh_red[4], sh_red2[4];
  __shared__ float redc[8][512];
  __shared__ float gl[4][16][16];
  __shared__ float em_s[512];
  const int b = blockIdx.x, tid = threadIdx.x;
  const int wave = tid >> 6, lane = tid & 63;
  const int bx = b & 15, by = b >> 4;      // phase-B role
  const int cr = tid >> 4, cu = tid & 15;  // cell role (tid<256)
  float c_reg = 0.f;
  float bg0=0,bg1=0,bg2=0,bg3=0, w00=0,w01=0,w02=0,w03=0;
  if (tid < 256){
    int uu = bx*16 + cu;
    bg0 = b_d[uu];       bg1 = b_d[256+uu];
    bg2 = b_d[512+uu];   bg3 = b_d[768+uu];
    w00 = Wx_d[uu];      w01 = Wx_d[256+uu];
    w02 = Wx_d[512+uu];  w03 = Wx_d[768+uu];
  }
  // ================= prologue (block-local) =================
  {
    const int lrow = lane & 15, kblk = lane >> 4, koff = kblk*8;
    // ep rows: [256t x 64] = eo[b] @ We^T (split MFMA); 8 waves x 2 M-tiles
    #pragma unroll
    for (int mi=0; mi<2; mi++){
      int mt = wave*2 + mi;
      f32x4 acc[4] = {};
      for (int ks=0; ks<16; ks++){
        int kb = ks*32 + koff;
        u32x8 ld = *(const u32x8*)(eo32 + ((size_t)b*T_ + mt*16 + lrow)*512 + kb);
        bf16x8 ah, al;
        #pragma unroll
        for (int j=0;j<8;j++){ ah[j]=(short)(ld[j]&0xFFFFu); al[j]=(short)(ld[j]>>16); }
        #pragma unroll
        for (int nf=0; nf<4; nf++){
          bf16x8 bh = *(const bf16x8*)(Wet_hi + (size_t)(nf*16+lrow)*512 + kb);
          bf16x8 bl = *(const bf16x8*)(Wet_lo + (size_t)(nf*16+lrow)*512 + kb);
          acc[nf] = __builtin_amdgcn_mfma_f32_16x16x32_bf16(ah, bh, acc[nf], 0,0,0);
          acc[nf] = __builtin_amdgcn_mfma_f32_16x16x32_bf16(ah, bl, acc[nf], 0,0,0);
          acc[nf] = __builtin_amdgcn_mfma_f32_16x16x32_bf16(al, bh, acc[nf], 0,0,0);
        }
      }
      #pragma unroll
      for (int nf=0; nf<4; nf++)
        #pragma unroll
        for (int r=0; r<4; r++)
          ep[((size_t)b*T_ + mt*16 + kblk*4 + r)*64 + nf*16 + lrow] = acc[nf][r];
    }
  }
  {   // enc-mean of own row
    float cacc[8] = {};
    const u32* eo = eo32 + (size_t)b*T_*512 + lane*8;
    #pragma unroll 8
    for (int tt=0; tt<32; tt++){
      int t = wave*32 + tt;
      u32x4 e0 = *(const u32x4*)(eo + (size_t)t*512);
      u32x4 e1 = *(const u32x4*)(eo + (size_t)t*512 + 4);
      #pragma unroll
      for (int j=0;j<4;j++){ cacc[j] += unpack2f(e0[j]); cacc[4+j] += unpack2f(e1[j]); }
    }
    #pragma unroll
    for (int j=0;j<8;j++) redc[wave][lane*8+j] = cacc[j];
    __syncthreads();
    if (tid < 256){
      float s0=0.f, s1=0.f;
      #pragma unroll
      for (int q=0;q<8;q++){ s0 += redc[q][tid]; s1 += redc[q][256+tid]; }
      em_s[tid] = s0*(1.f/T_); em_s[256+tid] = s1*(1.f/T_);
    }
    __syncthreads();
  }
  if (tid < 256){  // dec_h / dec_c (GEMV + tanh)
    float ah = b_ih[tid], ac = b_ic[tid];
    for (int k=0;k<512;k++){
      float e = em_s[k];
      ah += e*W_ih[(size_t)k*256 + tid];
      ac += e*W_ic[(size_t)k*256 + tid];
    }
    float h0 = tanhf(ah), c0 = tanhf(ac);
    sh_h[tid] = h0;
    hdp[(size_t)b*H_ + tid] = h0;                       // parity 0
    Ad32[(size_t)b*ADLD + 512 + tid] = packsplit(h0);   // h slot 0
    cd[(size_t)b*H_ + tid] = c0;
  }
  if (tid == 0){
    size_t xb = ((size_t)b*T_ + 255)*F_;
    py[b] = (x[xb] + x[xb+2])*0.5f;
  }
  if (tid >= 448) sh_v[tid-448] = v[tid-448];
  __syncthreads();
  // ================= main loop =================
  for (int s=0; s<=HOR_; s++){
    if (s > 0){
      cnt_wait(cntB + (size_t)((s-1)*16 + by)*FPAD, 16, tid);
      if (tid < 256) sh_h[tid] = hdp[(size_t)(s&1)*B_*H_ + (size_t)b*H_ + tid];
      __syncthreads();
      if (tid < 256){                    // head: y_{s-1}, py
        float p = sh_h[tid] * Wo[tid];
        p = wred_sum(p);
        if ((tid & 63) == 0) sh_red[tid>>6] = p;
      }
      __syncthreads();
      if (tid == 0){
        float y = sh_red[0]+sh_red[1]+sh_red[2]+sh_red[3] + bo[0];
        out[b*HOR_ + (s-1)] = y;
        py[b] = y;
      }
    }
    if (s == HOR_) break;
    {   // hWd
      float ssum = 0.f;
      for (int j=wave*32; j<wave*32+32; j++) ssum += sh_h[j]*Wd[(size_t)j*A_ + lane];
      red8[wave][lane] = ssum;
      __syncthreads();
      if (tid < 64){
        float a = 0.f;
        #pragma unroll
        for (int q=0;q<8;q++) a += red8[q][tid];
        sh_hwd[tid] = a;
      }
    }
    __syncthreads();
    {   // scores: 2 lanes per t
      int t = tid >> 1, aa = tid & 1;
      const float4* ep4 = (const float4*)(ep + ((size_t)(b*T_+t))*A_ + aa*32);
      float partial = 0.f;
      #pragma unroll
      for (int q=0;q<8;q++){
        float4 e4 = ep4[q];
        int a0 = aa*32 + q*4;
        partial += tanhf(e4.x + sh_hwd[a0+0]) * sh_v[a0+0];
        partial += tanhf(e4.y + sh_hwd[a0+1]) * sh_v[a0+1];
        partial += tanhf(e4.z + sh_hwd[a0+2]) * sh_v[a0+2];
        partial += tanhf(e4.w + sh_hwd[a0+3]) * sh_v[a0+3];
      }
      partial += __shfl_xor(partial, 1);
      if (aa == 0) sh_sc[t] = partial;
    }
    __syncthreads();
    if (tid < 256){                      // softmax over T
      float sc = sh_sc[tid];
      float m = wred_max(sc);
      if ((tid&63)==0) sh_red[tid>>6] = m;
      __syncthreads();
      m = fmaxf(fmaxf(sh_red[0],sh_red[1]), fmaxf(sh_red[2],sh_red[3]));
      float e = expf(sc - m);
      float su = wred_sum(e);
      if ((tid&63)==0) sh_red2[tid>>6] = su;
      __syncthreads();
      su = (sh_red2[0]+sh_red2[1])+(sh_red2[2]+sh_red2[3]);
      sh_w[tid] = e / su;
    } else { __syncthreads(); __syncthreads(); }
    __syncthreads();
    {   // context: wave w owns t in [w*32,+32), 8 cols per lane
      float cacc[8] = {};
      const u32* eo = eo32 + (size_t)b*T_*512 + lane*8;
      #pragma unroll 8
      for (int tt=0; tt<32; tt++){
        int t = wave*32 + tt;
        float wgt = sh_w[t];
        u32x4 e0 = *(const u32x4*)(eo + (size_t)t*512);
        u32x4 e1 = *(const u32x4*)(eo + (size_t)t*512 + 4);
        #pragma unroll
        for (int j=0;j<4;j++){
          cacc[j]   += wgt * unpack2f(e0[j]);
          cacc[4+j] += wgt * unpack2f(e1[j]);
        }
      }
      #pragma unroll
      for (int j=0;j<8;j++) redc[wave][lane*8+j] = cacc[j];
    }
    __syncthreads();
    if (tid < 256){
      float c0 = 0.f, c1 = 0.f;
      #pragma unroll
      for (int q=0;q<8;q++){ c0 += redc[q][tid]; c1 += redc[q][256+tid]; }
      Ad32[(size_t)b*ADLD + tid]       = packsplit(c0);
      Ad32[(size_t)b*ADLD + 256 + tid] = packsplit(c1);
    }
    __syncthreads();                     // drain ctx/py/out stores
    if (tid == 0)
      cnt_signal(cntA + (size_t)(s*16 + by)*FPAD);
    // ---- phase B: wait own tile's 16 row arrivals, GEMM, cell ----
    cnt_wait(cntA + (size_t)(s*16 + by)*FPAD, 16, tid);
    if (s == 0 && tid < 256)
      c_reg = cd[(size_t)(by*16 + cr)*H_ + bx*16 + cu];
    const int par = s & 1;
    if (wave < 4){
      const int g = wave;
      const int r16 = lane & 15, kb4 = lane >> 4;
      f32x4 acc = {0.f,0.f,0.f,0.f};
      const u32* ar = Ad32 + (size_t)(by*16 + r16)*ADLD;
      const u16* WH = W_hi + (size_t)(g*256 + bx*16 + r16)*768;
      const u16* WL = W_lo + (size_t)(g*256 + bx*16 + r16)*768;
      for (int ks=0; ks<24; ks++){
        int kb = ks*32 + kb4*8;
        int kp = (kb < 512) ? kb : (kb + (par<<8));   // parity slot for h
        u32x8 ld = *(const u32x8*)(ar + kp);
        bf16x8 ah, al;
        #pragma unroll
        for (int j=0;j<8;j++){ ah[j]=(short)(ld[j]&0xFFFFu); al[j]=(short)(ld[j]>>16); }
        bf16x8 bh = *(const bf16x8*)(WH + kb);
        bf16x8 bl = *(const bf16x8*)(WL + kb);
        acc = __builtin_amdgcn_mfma_f32_16x16x32_bf16(ah, bh, acc, 0,0,0);
        acc = __builtin_amdgcn_mfma_f32_16x16x32_bf16(ah, bl, acc, 0,0,0);
        acc = __builtin_amdgcn_mfma_f32_16x16x32_bf16(al, bh, acc, 0,0,0);
      }
      #pragma unroll
      for (int vv=0; vv<4; vv++) gl[g][kb4*4+vv][r16] = acc[vv];
    }
    __syncthreads();
    if (tid < 256){                      // cell: thread (cr,cu), c in register
      float pyr = py[by*16 + cr];
      float gi = gl[0][cr][cu] + bg0 + pyr*w00;
      float gf = gl[1][cr][cu] + bg1 + pyr*w01;
      float gg = gl[2][cr][cu] + bg2 + pyr*w02;
      float go = gl[3][cr][cu] + bg3 + pyr*w03;
      float cn = sigm(gf)*c_reg + sigm(gi)*tanhf(gg);
      float hn = sigm(go)*tanhf(cn);
      c_reg = cn;
      size_t ridx = (size_t)(by*16+cr)*H_ + bx*16+cu;
      hdp[(size_t)((s+1)&1)*B_*H_ + ridx] = hn;
      Ad32[(size_t)(by*16+cr)*ADLD + 512 + (((s+1)&1)<<8) + bx*16+cu] = packsplit(hn);
    }
    __syncthreads();                     // drain h stores
    if (tid == 0)
      cnt_signal(cntB + (size_t)(s*16 + by)*FPAD);
  }
}

extern "C" void kernel_launch(void* const* d_in, const int* in_sizes, int n_in,
                              void* d_out, int out_size, void* d_ws, size_t ws_size,
                              hipStream_t stream)
{
  const float* x    = (const float*)d_in[0];
  const float* W_sp = (const float*)d_in[1];
  const float* b_sp = (const float*)d_in[2];
  const float* Wx_ef= (const float*)d_in[3];
  const float* Wh_ef= (const float*)d_in[4];
  const float* b_ef = (const float*)d_in[5];
  const float* Wx_eb= (const float*)d_in[6];
  const float* Wh_eb= (const float*)d_in[7];
  const float* b_eb = (const float*)d_in[8];
  const float* We   = (const float*)d_in[9];
  const float* Wd   = (const float*)d_in[10];
  const float* v    = (const float*)d_in[11];
  const float* Wx_d = (const float*)d_in[12];
  const float* Wh_d = (const float*)d_in[13];
  const float* b_d  = (const float*)d_in[14];
  const float* W_ih = (const float*)d_in[15];
  const float* b_ih = (const float*)d_in[16];
  const float* W_ic = (const float*)d_in[17];
  const float* b_ic = (const float*)d_in[18];
  const float* Wo   = (const float*)d_in[19];
  const float* bo   = (const float*)d_in[20];
  float* out = (float*)d_out;

  char* base = (char*)d_ws;
  auto alloc = [&](size_t bytes)->char*{
    char* p = base; base += (bytes + 255) & ~(size_t)255; return p;
  };
  u16* Wenc_hi = (u16*)alloc((size_t)2*1024*448*2);
  u16* Wenc_lo = (u16*)alloc((size_t)2*1024*448*2);
  u16* Wdec_hi = (u16*)alloc((size_t)1024*768*2);
  u16* Wdec_lo = (u16*)alloc((size_t)1024*768*2);
  u16* Wet_hi  = (u16*)alloc((size_t)64*512*2);
  u16* Wet_lo  = (u16*)alloc((size_t)64*512*2);
  u32* hsp32   = (u32*)alloc((size_t)T_*B_*DSP_*4);
  u32* hbuf    = (u32*)alloc((size_t)2*2*B_*H_*4);   // [parity][dir][b][u]
  u32* eo32    = (u32*)alloc((size_t)B_*T_*512*4);
  float* ep    = (float*)alloc((size_t)B_*T_*64*4);
  float* cd    = (float*)alloc((size_t)B_*H_*4);
  float* hdp   = (float*)alloc((size_t)2*B_*H_*4);   // parity h (fp32)
  u32* Ad32    = (u32*)alloc((size_t)B_*ADLD*4);
  float* pyb   = (float*)alloc((size_t)B_*4);
  int* bar     = (int*)alloc((size_t)8*T_*4);        // enc counters (r8)
  int* cntA    = (int*)alloc((size_t)HOR_*16*FPAD*4);
  int* cntB    = (int*)alloc((size_t)HOR_*16*FPAD*4);
  if ((size_t)(base - (char*)d_ws) > ws_size) return;

  // one-time weight conversions
  conv_w<<<dim3(1792),256,0,stream>>>(Wx_ef, Wh_ef, Wenc_hi, Wenc_lo, DSP_, 448, 1024);
  conv_w<<<dim3(1792),256,0,stream>>>(Wx_eb, Wh_eb, Wenc_hi+458752, Wenc_lo+458752, DSP_, 448, 1024);
  conv_w<<<dim3(3072),256,0,stream>>>(Wx_d+1024, Wh_d, Wdec_hi, Wdec_lo, 512, 768, 1024);
  conv_w<<<dim3(128),256,0,stream>>>(We, We, Wet_hi, Wet_lo, 512, 512, 64);

  spatial_proj<<<dim3(256),192,0,stream>>>(x, W_sp, b_sp, hsp32);

  hipMemsetAsync(hbuf, 0, (size_t)2*B_*H_*4, stream);          // parity-0 h = 0
  hipMemsetAsync(bar, 0, (size_t)8*T_*4, stream);              // enc counters
  hipMemsetAsync(cntA, 0, (size_t)HOR_*16*FPAD*4, stream);     // dec counters
  hipMemsetAsync(cntB, 0, (size_t)HOR_*16*FPAD*4, stream);

  enc_scan<<<dim3(ENC_NBLK), dim3(256), 2*4*16*WSTR*2, stream>>>(
      hsp32, Wenc_hi, Wenc_lo, b_ef, b_eb, hbuf, eo32, bar);

  dec_scan<<<dim3(256),512,0,stream>>>(
      eo32, Wet_hi, Wet_lo, W_ih, b_ih, W_ic, b_ic, x, ep,
      Wd, v, Wo, bo, Wdec_hi, Wdec_lo, b_d, Wx_d,
      hdp, cd, Ad32, pyb, out, cntA, cntB);
}

// Round 11
// 5554.941 us; speedup vs baseline: 2.1727x; 1.0383x over previous
//
#include <hip/hip_runtime.h>
#include <cmath>

#define B_ 256
#define T_ 256
#define F_ 40
#define H_ 256
#define A_ 64
#define HOR_ 60
#define DSP_ 192
#define ENC_NBLK 128
#define GRP_SZ 16     // blocks per enc barrier group (one dir x mtile)
#define WSTR 456      // LDS weight row stride in u16 (448 + pad)
#define FPAD 32       // counter stride in ints (128 B -> own cacheline)
#define ADLD 1024     // Ad32 row stride: ctx(512) | h_even(256) | h_odd(256)
#define CT 56         // eo t-rows cached in LDS per decoder block

typedef unsigned short u16;
typedef unsigned int u32;
typedef __attribute__((ext_vector_type(8))) short bf16x8;
typedef __attribute__((ext_vector_type(4))) float f32x4;
typedef __attribute__((ext_vector_type(8))) u32 u32x8;
typedef __attribute__((ext_vector_type(4))) u32 u32x4;

__device__ __forceinline__ float sigm(float x){ return 1.f/(1.f+expf(-x)); }

__device__ __forceinline__ u16 f2bf(float x){
  u32 u = __float_as_uint(x);
  u32 r = (u + 0x7FFFu + ((u>>16)&1u)) >> 16;
  return (u16)r;
}
__device__ __forceinline__ float bf2f(u16 h){ return __uint_as_float(((u32)h)<<16); }
__device__ __forceinline__ u32 packsplit(float x){
  u16 hi = f2bf(x);
  u16 lo = f2bf(x - bf2f(hi));
  return (u32)hi | ((u32)lo<<16);
}
__device__ __forceinline__ float unpack2f(u32 v){
  return __uint_as_float(v<<16) + __uint_as_float(v & 0xFFFF0000u);
}

__device__ __forceinline__ float wred_sum(float v){
  #pragma unroll
  for (int o=32;o>0;o>>=1) v += __shfl_xor(v,o);
  return v;
}
__device__ __forceinline__ float wred_max(float v){
  #pragma unroll
  for (int o=32;o>0;o>>=1) v = fmaxf(v,__shfl_xor(v,o));
  return v;
}

// PROVEN barrier primitive (r4/r8/r10, replay-stable): arrival = RELEASE
// fetch_add; wait = tid0 ACQUIRE-spin (every poll invalidates) + syncthreads.
__device__ __forceinline__ void cnt_signal(int* c){
  __hip_atomic_fetch_add(c, 1, __ATOMIC_RELEASE, __HIP_MEMORY_SCOPE_AGENT);
}
__device__ __forceinline__ void cnt_wait(const int* c, int n, int tid){
  if (tid == 0){
    while (__hip_atomic_load(c, __ATOMIC_ACQUIRE, __HIP_MEMORY_SCOPE_AGENT) < n)
      __builtin_amdgcn_s_sleep(1);
  }
  __syncthreads();
}

// ---- weight conversion: dst[n][k] (hi/lo bf16) = src[k][n], src = [Wx ; Wh] ----
__global__ void conv_w(const float* __restrict__ Wx, const float* __restrict__ Wh,
                       u16* __restrict__ hi, u16* __restrict__ lo,
                       int KX, int Ktot, int N){
  int idx = blockIdx.x*256 + threadIdx.x;
  if (idx >= N*Ktot) return;
  int n = idx / Ktot, k = idx - n*Ktot;
  float w = (k < KX) ? Wx[(size_t)k*N + n] : Wh[(size_t)(k-KX)*N + n];
  u16 h = f2bf(w);
  hi[idx] = h;
  lo[idx] = f2bf(w - bf2f(h));
}

// ---- spatial projection: hsp32[t][b][192] packed = x[b][t][:40] @ W_sp + b_sp ----
__global__ __launch_bounds__(192) void spatial_proj(
    const float* __restrict__ x, const float* __restrict__ W, const float* __restrict__ bsp,
    u32* __restrict__ hsp32){
  __shared__ float Ws[40][192];
  __shared__ float xr[40];
  int t = blockIdx.x, tid = threadIdx.x;
  for (int i = tid; i < 40*192; i += 192){ int k = i/192, c = i-k*192; Ws[k][c] = W[i]; }
  float bb = bsp[tid];
  __syncthreads();
  for (int b=0; b<B_; b++){
    if (tid < 40) xr[tid] = x[((size_t)b*T_ + t)*F_ + tid];
    __syncthreads();
    float acc = bb;
    #pragma unroll
    for (int k=0;k<40;k++) acc += xr[k]*Ws[k][tid];
    hsp32[((size_t)t*B_ + b)*DSP_ + tid] = packsplit(acc);
    __syncthreads();
  }
}

// ---- persistent bidirectional encoder scan (r8/r10 proven version, verbatim) ----
__global__ __launch_bounds__(256) void enc_scan(
    const u32* __restrict__ hsp32,
    const u16* __restrict__ W_hi, const u16* __restrict__ W_lo,
    const float* __restrict__ b_ef, const float* __restrict__ b_eb,
    u32* __restrict__ hbuf, u32* __restrict__ eo32, int* __restrict__ bar)
{
  extern __shared__ u16 smem[];
  u16* Whi = smem;                    // [4 gates][16 units][WSTR]
  u16* Wlo = smem + 4*16*WSTR;
  const int bid = blockIdx.x;
  const int grp = bid & 7;            // dir*4 + mtile
  const int nt  = bid >> 3;
  const int dir = grp >> 2;
  const int m0  = (grp & 3) * 64;
  const int u0  = nt * 16;
  const int tid = threadIdx.x;
  const int wave = tid >> 6, lane = tid & 63;
  const int lrow = lane & 15, kblk = lane >> 4;
  const int koff = kblk * 8;
  {
    const size_t wbase = ((size_t)dir*1024 + u0) * 448;
    for (int idx = tid; idx < 4*16*448; idx += 256){
      int g = idx / (16*448);
      int r = idx - g*(16*448);
      int j = r / 448;
      int k = r - j*448;
      size_t go = wbase + ((size_t)g*256 + j)*448 + k;
      Whi[(g*16 + j)*WSTR + k] = W_hi[go];
      Wlo[(g*16 + j)*WSTR + k] = W_lo[go];
    }
  }
  const float* bias = dir ? b_eb : b_ef;
  float bg4[4];
  #pragma unroll
  for (int g=0; g<4; g++) bg4[g] = bias[g*H_ + u0 + lrow];
  __syncthreads();

  const int mrow = m0 + wave*16;
  const int arow = mrow + lrow;
  u32* hP0 = hbuf + (size_t)dir*(B_*H_);
  u32* hP1 = hbuf + (size_t)(2+dir)*(B_*H_);
  int* gbar = bar + grp*T_;
  float c_reg[4] = {0.f,0.f,0.f,0.f};

  for (int s=0; s<T_; s++){
    const int t = dir ? (T_-1-s) : s;
    f32x4 acc[4] = {};
    // ---- x part (k 0..191): independent of h -> before barrier ----
    const u32* abase = hsp32 + ((size_t)t*B_ + arow)*DSP_;
    #pragma unroll
    for (int ks=0; ks<6; ks++){
      int kb = ks*32 + koff;
      u32x8 la = *(const u32x8*)(abase + kb);
      bf16x8 ah, al;
      #pragma unroll
      for (int j=0;j<8;j++){ ah[j]=(short)(la[j]&0xFFFFu); al[j]=(short)(la[j]>>16); }
      #pragma unroll
      for (int g=0; g<4; g++){
        bf16x8 bh = *(const bf16x8*)(Whi + (g*16+lrow)*WSTR + kb);
        bf16x8 bl = *(const bf16x8*)(Wlo + (g*16+lrow)*WSTR + kb);
        acc[g] = __builtin_amdgcn_mfma_f32_16x16x32_bf16(ah, bh, acc[g], 0,0,0);
        acc[g] = __builtin_amdgcn_mfma_f32_16x16x32_bf16(ah, bl, acc[g], 0,0,0);
        acc[g] = __builtin_amdgcn_mfma_f32_16x16x32_bf16(al, bh, acc[g], 0,0,0);
      }
    }
    // ---- wait for group's h(s-1) ----
    if (s > 0){
      if (tid == 0){
        while (__hip_atomic_load(&gbar[s-1], __ATOMIC_ACQUIRE, __HIP_MEMORY_SCOPE_AGENT) < GRP_SZ)
          __builtin_amdgcn_s_sleep(1);
      }
      __syncthreads();
    }
    const u32* hin = (s & 1) ? hP1 : hP0;
    u32* hout      = (s & 1) ? hP0 : hP1;
    // ---- h part (k 192..447) ----
    const u32* hbase = hin + (size_t)arow*H_;
    #pragma unroll
    for (int ks=0; ks<8; ks++){
      int kb = ks*32 + koff;
      u32x8 la = *(const u32x8*)(hbase + kb);
      bf16x8 ah, al;
      #pragma unroll
      for (int j=0;j<8;j++){ ah[j]=(short)(la[j]&0xFFFFu); al[j]=(short)(la[j]>>16); }
      #pragma unroll
      for (int g=0; g<4; g++){
        bf16x8 bh = *(const bf16x8*)(Whi + (g*16+lrow)*WSTR + 192 + kb);
        bf16x8 bl = *(const bf16x8*)(Wlo + (g*16+lrow)*WSTR + 192 + kb);
        acc[g] = __builtin_amdgcn_mfma_f32_16x16x32_bf16(ah, bh, acc[g], 0,0,0);
        acc[g] = __builtin_amdgcn_mfma_f32_16x16x32_bf16(ah, bl, acc[g], 0,0,0);
        acc[g] = __builtin_amdgcn_mfma_f32_16x16x32_bf16(al, bh, acc[g], 0,0,0);
      }
    }
    // ---- cell (c in registers), h/eo writes ----
    #pragma unroll
    for (int r=0; r<4; r++){
      int brow = mrow + kblk*4 + r;
      float gi = acc[0][r] + bg4[0];
      float gf = acc[1][r] + bg4[1];
      float gg = acc[2][r] + bg4[2];
      float go = acc[3][r] + bg4[3];
      float cn = sigm(gf)*c_reg[r] + sigm(gi)*tanhf(gg);
      float hn = sigm(go)*tanhf(cn);
      c_reg[r] = cn;
      u32 hp = packsplit(hn);
      hout[(size_t)brow*H_ + u0 + lrow] = hp;
      eo32[((size_t)brow*T_ + t)*512 + dir*H_ + u0 + lrow] = hp;  // normal store: seed L2/L3
    }
    if (s == T_-1) break;
    __syncthreads();
    if (tid == 0)
      __hip_atomic_fetch_add(&gbar[s], 1, __ATOMIC_RELEASE, __HIP_MEMORY_SCOPE_AGENT);
  }
}

// ---- persistent decoder with self-contained prologue ----
// 256 blocks x 512 thr. Prologue: ep rows (MFMA), enc-mean, dec_h/dec_c, py,
// + stage eo t<CT into LDS. Loop: phase A attn (row b), phase B LSTM tile
// (rows 16*(b>>4).., units 16*(b&15)..) with 8-wave K-split. h parity-buffered.
__global__ __launch_bounds__(512) void dec_scan(
    const u32* __restrict__ eo32,
    const u16* __restrict__ Wet_hi, const u16* __restrict__ Wet_lo,
    const float* __restrict__ W_ih, const float* __restrict__ b_ih,
    const float* __restrict__ W_ic, const float* __restrict__ b_ic,
    const float* __restrict__ x, float* __restrict__ ep,
    const float* __restrict__ Wd, const float* __restrict__ v,
    const float* __restrict__ Wo, const float* __restrict__ bo,
    const u16* __restrict__ W_hi, const u16* __restrict__ W_lo,
    const float* __restrict__ b_d, const float* __restrict__ Wx_d,
    float* __restrict__ hdp, float* __restrict__ cd,
    u32* __restrict__ Ad32, float* __restrict__ py,
    float* __restrict__ out, int* __restrict__ cntA, int* __restrict__ cntB)
{
  __shared__ float sh_h[256], sh_hwd[64], sh_v[64], sh_sc[256], sh_w[256];
  __shared__ float red8[8][64];
  __shared__ float sh_red[4], sh_red2[4];
  __shared__ float redc[8][512];
  __shared__ float gl[8][16][16];
  __shared__ float em_s[512];
  __shared__ u32 eoL[CT*512];          // eo t<CT cache (114 KB)
  const int b = blockIdx.x, tid = threadIdx.x;
  const int wave = tid >> 6, lane = tid & 63;
  const int bx = b & 15, by = b >> 4;      // phase-B role
  const int cr = tid >> 4, cu = tid & 15;  // cell role (tid<256)
  float c_reg = 0.f;
  float bg0=0,bg1=0,bg2=0,bg3=0, w00=0,w01=0,w02=0,w03=0;
  if (tid < 256){
    int uu = bx*16 + cu;
    bg0 = b_d[uu];       bg1 = b_d[256+uu];
    bg2 = b_d[512+uu];   bg3 = b_d[768+uu];
    w00 = Wx_d[uu];      w01 = Wx_d[256+uu];
    w02 = Wx_d[512+uu];  w03 = Wx_d[768+uu];
  }
  // ================= prologue (block-local) =================
  {   // stage eo t<CT into LDS (coalesced u32x4)
    const u32* src = eo32 + (size_t)b*T_*512;
    for (int i = tid; i < CT*512/4; i += 512)
      ((u32x4*)eoL)[i] = *(const u32x4*)(src + (size_t)i*4);
  }
  {
    const int lrow = lane & 15, kblk = lane >> 4, koff = kblk*8;
    // ep rows: [256t x 64] = eo[b] @ We^T (split MFMA); 8 waves x 2 M-tiles
    #pragma unroll
    for (int mi=0; mi<2; mi++){
      int mt = wave*2 + mi;
      f32x4 acc[4] = {};
      for (int ks=0; ks<16; ks++){
        int kb = ks*32 + koff;
        u32x8 ld = *(const u32x8*)(eo32 + ((size_t)b*T_ + mt*16 + lrow)*512 + kb);
        bf16x8 ah, al;
        #pragma unroll
        for (int j=0;j<8;j++){ ah[j]=(short)(ld[j]&0xFFFFu); al[j]=(short)(ld[j]>>16); }
        #pragma unroll
        for (int nf=0; nf<4; nf++){
          bf16x8 bh = *(const bf16x8*)(Wet_hi + (size_t)(nf*16+lrow)*512 + kb);
          bf16x8 bl = *(const bf16x8*)(Wet_lo + (size_t)(nf*16+lrow)*512 + kb);
          acc[nf] = __builtin_amdgcn_mfma_f32_16x16x32_bf16(ah, bh, acc[nf], 0,0,0);
          acc[nf] = __builtin_amdgcn_mfma_f32_16x16x32_bf16(ah, bl, acc[nf], 0,0,0);
          acc[nf] = __builtin_amdgcn_mfma_f32_16x16x32_bf16(al, bh, acc[nf], 0,0,0);
        }
      }
      #pragma unroll
      for (int nf=0; nf<4; nf++)
        #pragma unroll
        for (int r=0; r<4; r++)
          ep[((size_t)b*T_ + mt*16 + kblk*4 + r)*64 + nf*16 + lrow] = acc[nf][r];
    }
  }
  {   // enc-mean of own row
    float cacc[8] = {};
    const u32* eo = eo32 + (size_t)b*T_*512 + lane*8;
    #pragma unroll 8
    for (int tt=0; tt<32; tt++){
      int t = wave*32 + tt;
      u32x4 e0 = *(const u32x4*)(eo + (size_t)t*512);
      u32x4 e1 = *(const u32x4*)(eo + (size_t)t*512 + 4);
      #pragma unroll
      for (int j=0;j<4;j++){ cacc[j] += unpack2f(e0[j]); cacc[4+j] += unpack2f(e1[j]); }
    }
    #pragma unroll
    for (int j=0;j<8;j++) redc[wave][lane*8+j] = cacc[j];
    __syncthreads();
    if (tid < 256){
      float s0=0.f, s1=0.f;
      #pragma unroll
      for (int q=0;q<8;q++){ s0 += redc[q][tid]; s1 += redc[q][256+tid]; }
      em_s[tid] = s0*(1.f/T_); em_s[256+tid] = s1*(1.f/T_);
    }
    __syncthreads();
  }
  if (tid < 256){  // dec_h / dec_c (GEMV + tanh)
    float ah = b_ih[tid], ac = b_ic[tid];
    for (int k=0;k<512;k++){
      float e = em_s[k];
      ah += e*W_ih[(size_t)k*256 + tid];
      ac += e*W_ic[(size_t)k*256 + tid];
    }
    float h0 = tanhf(ah), c0 = tanhf(ac);
    sh_h[tid] = h0;
    hdp[(size_t)b*H_ + tid] = h0;                       // parity 0
    Ad32[(size_t)b*ADLD + 512 + tid] = packsplit(h0);   // h slot 0
    cd[(size_t)b*H_ + tid] = c0;
  }
  if (tid == 0){
    size_t xb = ((size_t)b*T_ + 255)*F_;
    py[b] = (x[xb] + x[xb+2])*0.5f;
  }
  if (tid >= 448) sh_v[tid-448] = v[tid-448];
  __syncthreads();
  // ================= main loop =================
  for (int s=0; s<=HOR_; s++){
    if (s > 0){
      cnt_wait(cntB + (size_t)((s-1)*16 + by)*FPAD, 16, tid);
      if (tid < 256) sh_h[tid] = hdp[(size_t)(s&1)*B_*H_ + (size_t)b*H_ + tid];
      __syncthreads();
      if (tid < 256){                    // head: y_{s-1}, py
        float p = sh_h[tid] * Wo[tid];
        p = wred_sum(p);
        if ((tid & 63) == 0) sh_red[tid>>6] = p;
      }
      __syncthreads();
      if (tid == 0){
        float y = sh_red[0]+sh_red[1]+sh_red[2]+sh_red[3] + bo[0];
        out[b*HOR_ + (s-1)] = y;
        py[b] = y;
      }
    }
    if (s == HOR_) break;
    {   // hWd
      float ssum = 0.f;
      for (int j=wave*32; j<wave*32+32; j++) ssum += sh_h[j]*Wd[(size_t)j*A_ + lane];
      red8[wave][lane] = ssum;
      __syncthreads();
      if (tid < 64){
        float a = 0.f;
        #pragma unroll
        for (int q=0;q<8;q++) a += red8[q][tid];
        sh_hwd[tid] = a;
      }
    }
    __syncthreads();
    {   // scores: 2 lanes per t
      int t = tid >> 1, aa = tid & 1;
      const float4* ep4 = (const float4*)(ep + ((size_t)(b*T_+t))*A_ + aa*32);
      float partial = 0.f;
      #pragma unroll
      for (int q=0;q<8;q++){
        float4 e4 = ep4[q];
        int a0 = aa*32 + q*4;
        partial += tanhf(e4.x + sh_hwd[a0+0]) * sh_v[a0+0];
        partial += tanhf(e4.y + sh_hwd[a0+1]) * sh_v[a0+1];
        partial += tanhf(e4.z + sh_hwd[a0+2]) * sh_v[a0+2];
        partial += tanhf(e4.w + sh_hwd[a0+3]) * sh_v[a0+3];
      }
      partial += __shfl_xor(partial, 1);
      if (aa == 0) sh_sc[t] = partial;
    }
    __syncthreads();
    if (tid < 256){                      // softmax over T
      float sc = sh_sc[tid];
      float m = wred_max(sc);
      if ((tid&63)==0) sh_red[tid>>6] = m;
      __syncthreads();
      m = fmaxf(fmaxf(sh_red[0],sh_red[1]), fmaxf(sh_red[2],sh_red[3]));
      float e = expf(sc - m);
      float su = wred_sum(e);
      if ((tid&63)==0) sh_red2[tid>>6] = su;
      __syncthreads();
      su = (sh_red2[0]+sh_red2[1])+(sh_red2[2]+sh_red2[3]);
      sh_w[tid] = e / su;
    } else { __syncthreads(); __syncthreads(); }
    __syncthreads();
    {   // context: wave w owns t in [w*32,+32); t<CT from LDS, else global
      float cacc[8] = {};
      const int t0 = wave*32, t1 = t0 + 32;
      const int tL = (t1 < CT) ? t1 : CT;
      for (int t=t0; t<tL; ++t){
        float wgt = sh_w[t];
        const u32* p = eoL + t*512 + lane*8;
        u32x4 e0 = *(const u32x4*)p;
        u32x4 e1 = *(const u32x4*)(p + 4);
        #pragma unroll
        for (int j=0;j<4;j++){
          cacc[j]   += wgt * unpack2f(e0[j]);
          cacc[4+j] += wgt * unpack2f(e1[j]);
        }
      }
      const u32* eo = eo32 + (size_t)b*T_*512 + lane*8;
      const int tG = (t0 > CT) ? t0 : CT;
      #pragma unroll 4
      for (int t=tG; t<t1; ++t){
        float wgt = sh_w[t];
        u32x4 e0 = *(const u32x4*)(eo + (size_t)t*512);
        u32x4 e1 = *(const u32x4*)(eo + (size_t)t*512 + 4);
        #pragma unroll
        for (int j=0;j<4;j++){
          cacc[j]   += wgt * unpack2f(e0[j]);
          cacc[4+j] += wgt * unpack2f(e1[j]);
        }
      }
      #pragma unroll
      for (int j=0;j<8;j++) redc[wave][lane*8+j] = cacc[j];
    }
    __syncthreads();
    if (tid < 256){
      float c0 = 0.f, c1 = 0.f;
      #pragma unroll
      for (int q=0;q<8;q++){ c0 += redc[q][tid]; c1 += redc[q][256+tid]; }
      Ad32[(size_t)b*ADLD + tid]       = packsplit(c0);
      Ad32[(size_t)b*ADLD + 256 + tid] = packsplit(c1);
    }
    __syncthreads();                     // drain ctx/py/out stores
    if (tid == 0)
      cnt_signal(cntA + (size_t)(s*16 + by)*FPAD);
    // ---- phase B: wait own tile's 16 row arrivals; 8-wave K-split GEMM; cell ----
    cnt_wait(cntA + (size_t)(s*16 + by)*FPAD, 16, tid);
    if (s == 0 && tid < 256)
      c_reg = cd[(size_t)(by*16 + cr)*H_ + bx*16 + cu];
    const int par = s & 1;
    {
      const int g = wave & 3, kh = wave >> 2;
      const int r16 = lane & 15, kb4 = lane >> 4;
      f32x4 acc = {0.f,0.f,0.f,0.f};
      const u32* ar = Ad32 + (size_t)(by*16 + r16)*ADLD;
      const u16* WH = W_hi + (size_t)(g*256 + bx*16 + r16)*768;
      const u16* WL = W_lo + (size_t)(g*256 + bx*16 + r16)*768;
      for (int ks=kh*12; ks<kh*12+12; ks++){
        int kb = ks*32 + kb4*8;
        int kp = (kb < 512) ? kb : (kb + (par<<8));   // parity slot for h
        u32x8 ld = *(const u32x8*)(ar + kp);
        bf16x8 ah, al;
        #pragma unroll
        for (int j=0;j<8;j++){ ah[j]=(short)(ld[j]&0xFFFFu); al[j]=(short)(ld[j]>>16); }
        bf16x8 bh = *(const bf16x8*)(WH + kb);
        bf16x8 bl = *(const bf16x8*)(WL + kb);
        acc = __builtin_amdgcn_mfma_f32_16x16x32_bf16(ah, bh, acc, 0,0,0);
        acc = __builtin_amdgcn_mfma_f32_16x16x32_bf16(ah, bl, acc, 0,0,0);
        acc = __builtin_amdgcn_mfma_f32_16x16x32_bf16(al, bh, acc, 0,0,0);
      }
      #pragma unroll
      for (int vv=0; vv<4; vv++) gl[wave][kb4*4+vv][r16] = acc[vv];
    }
    __syncthreads();
    if (tid < 256){                      // cell: thread (cr,cu), c in register
      float pyr = py[by*16 + cr];
      float gi = gl[0][cr][cu] + gl[4][cr][cu] + bg0 + pyr*w00;
      float gf = gl[1][cr][cu] + gl[5][cr][cu] + bg1 + pyr*w01;
      float gg = gl[2][cr][cu] + gl[6][cr][cu] + bg2 + pyr*w02;
      float go = gl[3][cr][cu] + gl[7][cr][cu] + bg3 + pyr*w03;
      float cn = sigm(gf)*c_reg + sigm(gi)*tanhf(gg);
      float hn = sigm(go)*tanhf(cn);
      c_reg = cn;
      size_t ridx = (size_t)(by*16+cr)*H_ + bx*16+cu;
      hdp[(size_t)((s+1)&1)*B_*H_ + ridx] = hn;
      Ad32[(size_t)(by*16+cr)*ADLD + 512 + (((s+1)&1)<<8) + bx*16+cu] = packsplit(hn);
    }
    __syncthreads();                     // drain h stores
    if (tid == 0)
      cnt_signal(cntB + (size_t)(s*16 + by)*FPAD);
  }
}

extern "C" void kernel_launch(void* const* d_in, const int* in_sizes, int n_in,
                              void* d_out, int out_size, void* d_ws, size_t ws_size,
                              hipStream_t stream)
{
  const float* x    = (const float*)d_in[0];
  const float* W_sp = (const float*)d_in[1];
  const float* b_sp = (const float*)d_in[2];
  const float* Wx_ef= (const float*)d_in[3];
  const float* Wh_ef= (const float*)d_in[4];
  const float* b_ef = (const float*)d_in[5];
  const float* Wx_eb= (const float*)d_in[6];
  const float* Wh_eb= (const float*)d_in[7];
  const float* b_eb = (const float*)d_in[8];
  const float* We   = (const float*)d_in[9];
  const float* Wd   = (const float*)d_in[10];
  const float* v    = (const float*)d_in[11];
  const float* Wx_d = (const float*)d_in[12];
  const float* Wh_d = (const float*)d_in[13];
  const float* b_d  = (const float*)d_in[14];
  const float* W_ih = (const float*)d_in[15];
  const float* b_ih = (const float*)d_in[16];
  const float* W_ic = (const float*)d_in[17];
  const float* b_ic = (const float*)d_in[18];
  const float* Wo   = (const float*)d_in[19];
  const float* bo   = (const float*)d_in[20];
  float* out = (float*)d_out;

  char* base = (char*)d_ws;
  auto alloc = [&](size_t bytes)->char*{
    char* p = base; base += (bytes + 255) & ~(size_t)255; return p;
  };
  u16* Wenc_hi = (u16*)alloc((size_t)2*1024*448*2);
  u16* Wenc_lo = (u16*)alloc((size_t)2*1024*448*2);
  u16* Wdec_hi = (u16*)alloc((size_t)1024*768*2);
  u16* Wdec_lo = (u16*)alloc((size_t)1024*768*2);
  u16* Wet_hi  = (u16*)alloc((size_t)64*512*2);
  u16* Wet_lo  = (u16*)alloc((size_t)64*512*2);
  u32* hsp32   = (u32*)alloc((size_t)T_*B_*DSP_*4);
  u32* hbuf    = (u32*)alloc((size_t)2*2*B_*H_*4);   // [parity][dir][b][u]
  u32* eo32    = (u32*)alloc((size_t)B_*T_*512*4);
  float* ep    = (float*)alloc((size_t)B_*T_*64*4);
  float* cd    = (float*)alloc((size_t)B_*H_*4);
  float* hdp   = (float*)alloc((size_t)2*B_*H_*4);   // parity h (fp32)
  u32* Ad32    = (u32*)alloc((size_t)B_*ADLD*4);
  float* pyb   = (float*)alloc((size_t)B_*4);
  int* bar     = (int*)alloc((size_t)8*T_*4);        // enc counters (r8)
  int* cntA    = (int*)alloc((size_t)HOR_*16*FPAD*4);
  int* cntB    = (int*)alloc((size_t)HOR_*16*FPAD*4);
  if ((size_t)(base - (char*)d_ws) > ws_size) return;

  // one-time weight conversions
  conv_w<<<dim3(1792),256,0,stream>>>(Wx_ef, Wh_ef, Wenc_hi, Wenc_lo, DSP_, 448, 1024);
  conv_w<<<dim3(1792),256,0,stream>>>(Wx_eb, Wh_eb, Wenc_hi+458752, Wenc_lo+458752, DSP_, 448, 1024);
  conv_w<<<dim3(3072),256,0,stream>>>(Wx_d+1024, Wh_d, Wdec_hi, Wdec_lo, 512, 768, 1024);
  conv_w<<<dim3(128),256,0,stream>>>(We, We, Wet_hi, Wet_lo, 512, 512, 64);

  spatial_proj<<<dim3(256),192,0,stream>>>(x, W_sp, b_sp, hsp32);

  hipMemsetAsync(hbuf, 0, (size_t)2*B_*H_*4, stream);          // parity-0 h = 0
  hipMemsetAsync(bar, 0, (size_t)8*T_*4, stream);              // enc counters
  hipMemsetAsync(cntA, 0, (size_t)HOR_*16*FPAD*4, stream);     // dec counters
  hipMemsetAsync(cntB, 0, (size_t)HOR_*16*FPAD*4, stream);

  enc_scan<<<dim3(ENC_NBLK), dim3(256), 2*4*16*WSTR*2, stream>>>(
      hsp32, Wenc_hi, Wenc_lo, b_ef, b_eb, hbuf, eo32, bar);

  dec_scan<<<dim3(256),512,0,stream>>>(
      eo32, Wet_hi, Wet_lo, W_ih, b_ih, W_ic, b_ic, x, ep,
      Wd, v, Wo, bo, Wdec_hi, Wdec_lo, b_d, Wx_d,
      hdp, cd, Ad32, pyb, out, cntA, cntB);
}